// Round 2
// baseline (286.494 us; speedup 1.0000x reference)
//
#include <hip/hip_runtime.h>
#include <stdint.h>

#define TEMPERATURE 0.07f
#define MARGIN 0.1f
#define D_DIM 512          // elements per row
#define BM 256
#define BN 256
#define QSCALE 32.0f       // pre-quantization scale (2^5)
#define SCALE_BYTE 0x7A7A7A7A  // e8m0 2^-5 replicated (compensates QSCALE^2)

// Packed fragment-major layout (per matrix, N*512 bytes):
//   elem [row][k] -> (row>>4)*8192 + (k>>5)*512 + (row&15)*32 + (k&31)
// Panel = 16 rows (8192 B). K-step chunk of a panel = 1024 B at +ks*1024.
// For mfma_scale_f32_32x32x64_f8f6f4, lane L's fragment within a staged
// panel-PAIR region (2048 B) at linear addr
//   a = ((L>>4)&1)*1024 + (L>>5)*512 + (L&15)*32  (+16 for hi half)
// LDS image is stored XOR-swizzled: image[x] = orig[x ^ ((x>>3)&0x70)]
// (involution; spreads the 64 lanes of a ds_read_b128 evenly over all 8
// 4-bank groups). The permutation is applied on the global SOURCE side of
// global_load_lds (dest must stay linear), and on the read address.

typedef int v8i32 __attribute__((ext_vector_type(8)));
typedef int v4i32 __attribute__((ext_vector_type(4)));
typedef float f32x16 __attribute__((ext_vector_type(16)));

__device__ __forceinline__ float softplus(float x) {
    return fmaxf(x, 0.0f) + __logf(1.0f + __expf(-fabsf(x)));
}

__device__ __forceinline__ void load_lds16(const unsigned char* g,
                                           unsigned char* l) {
    __builtin_amdgcn_global_load_lds(
        (const __attribute__((address_space(1))) unsigned int*)g,
        (__attribute__((address_space(3))) unsigned int*)l, 16, 0, 0);
}

// Fused: L2-normalize row of S and T, quantize to e4m3 (x32), write packed
// fragment-major layout (via LDS so global writes are one contiguous 8 KB
// panel per matrix), and emit the diagonal correction term.
// One wave per row; 16 rows (one panel) per 1024-thread block.
__global__ __launch_bounds__(1024) void norm_quant_pack_kernel(
    const float* __restrict__ s_in, const float* __restrict__ t_in,
    unsigned char* __restrict__ sp, unsigned char* __restrict__ tp,
    float* __restrict__ corr) {
    __shared__ unsigned char pls[16384];  // [0,8192) S panel, [8192,16384) T
    const int wave = threadIdx.x >> 6;
    const int lane = threadIdx.x & 63;
    const int row = blockIdx.x * 16 + wave;
    const float4* s4 = (const float4*)(s_in + (size_t)row * D_DIM);
    const float4* t4 = (const float4*)(t_in + (size_t)row * D_DIM);
    float4 a0 = s4[lane * 2], a1 = s4[lane * 2 + 1];
    float4 b0 = t4[lane * 2], b1 = t4[lane * 2 + 1];
    float ss = a0.x * a0.x + a0.y * a0.y + a0.z * a0.z + a0.w * a0.w +
               a1.x * a1.x + a1.y * a1.y + a1.z * a1.z + a1.w * a1.w;
    float tt = b0.x * b0.x + b0.y * b0.y + b0.z * b0.z + b0.w * b0.w +
               b1.x * b1.x + b1.y * b1.y + b1.z * b1.z + b1.w * b1.w;
    float st = a0.x * b0.x + a0.y * b0.y + a0.z * b0.z + a0.w * b0.w +
               a1.x * b1.x + a1.y * b1.y + a1.z * b1.z + a1.w * b1.w;
#pragma unroll
    for (int off = 32; off > 0; off >>= 1) {
        ss += __shfl_down(ss, off);
        tt += __shfl_down(tt, off);
        st += __shfl_down(st, off);
    }
    ss = __shfl(ss, 0);
    tt = __shfl(tt, 0);
    const float ns = fmaxf(sqrtf(ss), 1e-12f);
    const float nt = fmaxf(sqrtf(tt), 1e-12f);
    if (lane == 0) {
        const float l = st / (ns * nt) * (1.0f / TEMPERATURE);
        corr[row] = softplus(-l - MARGIN) - softplus(l - MARGIN);
    }
    const float is = QSCALE / ns, it = QSCALE / nt;
    int s_lo = 0, s_hi = 0, t_lo = 0, t_hi = 0;
    s_lo = __builtin_amdgcn_cvt_pk_fp8_f32(a0.x * is, a0.y * is, s_lo, false);
    s_lo = __builtin_amdgcn_cvt_pk_fp8_f32(a0.z * is, a0.w * is, s_lo, true);
    s_hi = __builtin_amdgcn_cvt_pk_fp8_f32(a1.x * is, a1.y * is, s_hi, false);
    s_hi = __builtin_amdgcn_cvt_pk_fp8_f32(a1.z * is, a1.w * is, s_hi, true);
    t_lo = __builtin_amdgcn_cvt_pk_fp8_f32(b0.x * it, b0.y * it, t_lo, false);
    t_lo = __builtin_amdgcn_cvt_pk_fp8_f32(b0.z * it, b0.w * it, t_lo, true);
    t_hi = __builtin_amdgcn_cvt_pk_fp8_f32(b1.x * it, b1.y * it, t_hi, false);
    t_hi = __builtin_amdgcn_cvt_pk_fp8_f32(b1.z * it, b1.w * it, t_hi, true);
    // panel-local packed offset for this lane's k = 8*lane .. 8*lane+7
    const int local = (lane >> 4) * 2048 + ((lane >> 2) & 3) * 512 +
                      wave * 32 + (lane & 3) * 8;
    *(uint2*)(pls + local) = make_uint2((unsigned)s_lo, (unsigned)s_hi);
    *(uint2*)(pls + 8192 + local) = make_uint2((unsigned)t_lo, (unsigned)t_hi);
    __syncthreads();
    const int t = threadIdx.x;
    const size_t pbase = (size_t)blockIdx.x * 8192;
    *(uint2*)(sp + pbase + t * 8) = *(const uint2*)(pls + t * 8);
    *(uint2*)(tp + pbase + t * 8) = *(const uint2*)(pls + 8192 + t * 8);
}

// 256x256 logits tile per block; 8 waves 4x2, wave tile 64x128 = 2x4 of
// mfma_scale_f32_32x32x64_f8f6f4. LDS-staged (3 buffers x 32 KB), one
// barrier + counted vmcnt(4) per K-step, stage-ahead depth 2.
__global__ __launch_bounds__(512, 1) void gemm_loss_kernel(
    const unsigned char* __restrict__ Sp, const unsigned char* __restrict__ Tp,
    float* __restrict__ partial) {
    __shared__ unsigned char lds[3 * 32768];
    __shared__ float wsums[8];

    const int tid = threadIdx.x;
    const int wave = tid >> 6;
    const int lane = tid & 63;
    const int wm = wave >> 1;   // 0..3
    const int wn = wave & 1;    // 0..1

    // XCD super-tile swizzle: grid 4096 = 64x64 tiles; per-XCD super-tile of
    // 8x4 blocks (S 1 MB + T 0.5 MB panels -> L2-resident); 32 blocks/XCD
    // concurrent (32 CUs x 1 block) = exactly one super-tile.
    const int b = blockIdx.x;
    const int xcd = b & 7;
    const int slot = b >> 3;          // 0..511
    const int sidx = slot >> 5;       // 0..15
    const int within = slot & 31;     // 0..31
    const int st_ = sidx * 8 + xcd;   // 0..127
    const int tm = (st_ >> 4) * 8 + (within >> 2);   // 0..63
    const int tn_ = (st_ & 15) * 4 + (within & 3);   // 0..63

    // ---- staging setup: 32 chunks/K-step (16 A panels + 16 B panels),
    // 4 chunks per wave, 1024 B each (one global_load_lds dwordx4 / chunk).
    // Global source is pre-swizzled per-lane (swz within each 128-B block).
    const int srcswz = lane * 16 ^ ((lane & 0x38) << 1);
    const unsigned char* gb[4];
    int lo[4];
#pragma unroll
    for (int j = 0; j < 4; ++j) {
        const int c = wave * 4 + j;
        if (c < 16) {
            gb[j] = Sp + (size_t)(tm * 16 + c) * 8192 + srcswz;
            lo[j] = c * 1024;
        } else {
            gb[j] = Tp + (size_t)(tn_ * 16 + (c - 16)) * 8192 + srcswz;
            lo[j] = 16384 + (c - 16) * 1024;
        }
    }

    // ---- fragment read addressing (swizzled), within a 2048-B pair region
    const int fl =
        ((lane >> 4) & 1) * 1024 + (lane >> 5) * 512 + (lane & 15) * 32;
    const int s0 = fl ^ ((fl >> 3) & 0x70);
    const int s1 = s0 ^ 16;
    const int aoff = wm * 2 * 2048;          // wave's A pair base (2 pairs)
    const int boff = 16384 + wn * 4 * 2048;  // wave's B pair base (4 pairs)

    f32x16 acc[2][4];
#pragma unroll
    for (int pa = 0; pa < 2; ++pa)
#pragma unroll
        for (int pb = 0; pb < 4; ++pb)
#pragma unroll
            for (int r = 0; r < 16; ++r) acc[pa][pb][r] = 0.0f;

    auto stage = [&](int buf, int ks) {
#pragma unroll
        for (int j = 0; j < 4; ++j)
            load_lds16(gb[j] + ks * 1024, &lds[buf * 32768 + lo[j]]);
    };
    auto compute = [&](int buf) {
        const unsigned char* base = &lds[buf * 32768];
        v8i32 aF[2], bF[4];
#pragma unroll
        for (int pa = 0; pa < 2; ++pa) {
            v4i32 l_ = *(const v4i32*)(base + aoff + pa * 2048 + s0);
            v4i32 h_ = *(const v4i32*)(base + aoff + pa * 2048 + s1);
            aF[pa] = __builtin_shufflevector(l_, h_, 0, 1, 2, 3, 4, 5, 6, 7);
        }
#pragma unroll
        for (int pb = 0; pb < 4; ++pb) {
            v4i32 l_ = *(const v4i32*)(base + boff + pb * 2048 + s0);
            v4i32 h_ = *(const v4i32*)(base + boff + pb * 2048 + s1);
            bF[pb] = __builtin_shufflevector(l_, h_, 0, 1, 2, 3, 4, 5, 6, 7);
        }
        __builtin_amdgcn_s_setprio(1);
#pragma unroll
        for (int pb = 0; pb < 4; ++pb)
#pragma unroll
            for (int pa = 0; pa < 2; ++pa)
                acc[pa][pb] = __builtin_amdgcn_mfma_scale_f32_32x32x64_f8f6f4(
                    aF[pa], bF[pb], acc[pa][pb], 0 /*cbsz*/, 0 /*blgp*/,
                    0, SCALE_BYTE, 0, SCALE_BYTE);
        __builtin_amdgcn_s_setprio(0);
    };

#define KPHASE(VM)                                           \
    asm volatile("s_waitcnt vmcnt(" #VM ")" ::: "memory");   \
    __builtin_amdgcn_sched_barrier(0);                       \
    __builtin_amdgcn_s_barrier();                            \
    __builtin_amdgcn_sched_barrier(0);

    // K = 512, 8 K-steps of 64. Data ks lives in buf ks%3.
    stage(0, 0);
    stage(1, 1);
    KPHASE(4) stage(2, 2); compute(0);
    KPHASE(4) stage(0, 3); compute(1);
    KPHASE(4) stage(1, 4); compute(2);
    KPHASE(4) stage(2, 5); compute(0);
    KPHASE(4) stage(0, 6); compute(1);
    KPHASE(4) stage(1, 7); compute(2);
    KPHASE(4) compute(0);
    KPHASE(0) compute(1);
#undef KPHASE

    // Uniform epilogue: sum softplus(logit - margin) over all elems.
    // softplus(z) = ln2*( (y+|y|)/2 + log2(1+2^(-|y|)) ), y = z*log2e;
    // log2 terms folded into one v_log per 16-elem group via a product.
    const float C1 = (1.0f / TEMPERATURE) * 1.4426950408889634f;  // log2e/T
    const float C2 = -MARGIN * 1.4426950408889634f;
    float ysum = 0.0f, asum = 0.0f, lsum = 0.0f;
#pragma unroll
    for (int pa = 0; pa < 2; ++pa)
#pragma unroll
        for (int pb = 0; pb < 4; ++pb) {
            float prod = 1.0f;
#pragma unroll
            for (int r = 0; r < 16; ++r) {
                const float y = fmaf(acc[pa][pb][r], C1, C2);
                ysum += y;
                const float ay = fabsf(y);
                asum += ay;
                prod = fmaf(prod, __builtin_amdgcn_exp2f(-ay), prod);
            }
            lsum += __builtin_amdgcn_logf(prod);
        }
    float total =
        fmaf(ysum + asum, 0.5f, lsum) * 0.6931471805599453f;  // * ln2
#pragma unroll
    for (int off = 32; off > 0; off >>= 1) total += __shfl_down(total, off);
    if (lane == 0) wsums[wave] = total;
    __syncthreads();
    if (tid == 0) {
        float t = 0.0f;
#pragma unroll
        for (int w = 0; w < 8; ++w) t += wsums[w];
        partial[b] = t;
    }
}

__global__ __launch_bounds__(256) void reduce_kernel(
    const float* __restrict__ partial, int nPartials,
    const float* __restrict__ corr, int nCorr, int N,
    float* __restrict__ out) {
    float s = 0.0f;
    for (int i = threadIdx.x; i < nPartials; i += 256) s += partial[i];
    for (int i = threadIdx.x; i < nCorr; i += 256) s += corr[i];
#pragma unroll
    for (int off = 32; off > 0; off >>= 1) s += __shfl_down(s, off);
    __shared__ float ws[4];
    const int wave = threadIdx.x >> 6;
    const int lane = threadIdx.x & 63;
    if (lane == 0) ws[wave] = s;
    __syncthreads();
    if (threadIdx.x == 0) out[0] = (ws[0] + ws[1] + ws[2] + ws[3]) / (float)N;
}

extern "C" void kernel_launch(void* const* d_in, const int* in_sizes, int n_in,
                              void* d_out, int out_size, void* d_ws, size_t ws_size,
                              hipStream_t stream) {
    (void)n_in; (void)out_size; (void)ws_size;
    const float* s_in = (const float*)d_in[0];
    const float* t_in = (const float*)d_in[1];
    const int N = in_sizes[0] / D_DIM;  // 16384

    unsigned char* sp = (unsigned char*)d_ws;                    // N*512 fp8 packed
    unsigned char* tp = sp + (size_t)N * D_DIM;                  // N*512 fp8 packed
    float* partial = (float*)(tp + (size_t)N * D_DIM);           // 4096 floats
    const int nPartials = (N / BM) * (N / BN);
    float* corr = partial + nPartials;                           // N floats

    norm_quant_pack_kernel<<<N / 16, 1024, 0, stream>>>(s_in, t_in, sp, tp,
                                                        corr);
    gemm_loss_kernel<<<nPartials, 512, 0, stream>>>(sp, tp, partial);
    reduce_kernel<<<1, 256, 0, stream>>>(partial, nPartials, corr, N, N,
                                         (float*)d_out);
}

// Round 3
// 267.810 us; speedup vs baseline: 1.0698x; 1.0698x over previous
//
#include <hip/hip_runtime.h>
#include <stdint.h>

#define TEMPERATURE 0.07f
#define MARGIN 0.1f
#define D_DIM 512          // elements per row
#define BM 128
#define BN 256
#define QSCALE 32.0f       // pre-quantization scale (2^5)
#define SCALE_BYTE 0x7A7A7A7A  // e8m0 2^-5 replicated (compensates QSCALE^2)

// Packed fragment-major layout (per matrix, N*512 bytes):
//   elem [row][k] -> (row>>4)*8192 + (k>>5)*512 + (row&15)*32 + (k&31)
// Panel = 16 rows (8192 B); pair-region = 2 panels (16384 B) = 32 rows.
// mfma_scale_f32_32x32x64_f8f6f4 lane-L fragment of a pair at kstep ks:
//   global: pair*16384 + ((L>>4)&1)*8192 + (L>>5)*512 + (L&15)*32 + ks*1024
// LDS-staged B chunks (1024 B each, per panel per kstep) are stored
// XOR-swizzled: image[d] = orig[d ^ ((d>>3)&0x70)] within each chunk,
// applied on the global SOURCE side of global_load_lds (dest stays linear)
// and on the ds_read address.

typedef int v8i32 __attribute__((ext_vector_type(8)));
typedef int v4i32 __attribute__((ext_vector_type(4)));
typedef float f32x16 __attribute__((ext_vector_type(16)));

__device__ __forceinline__ float softplus(float x) {
    return fmaxf(x, 0.0f) + __logf(1.0f + __expf(-fabsf(x)));
}

__device__ __forceinline__ void load_lds16(const unsigned char* g,
                                           unsigned char* l) {
    __builtin_amdgcn_global_load_lds(
        (const __attribute__((address_space(1))) unsigned int*)g,
        (__attribute__((address_space(3))) unsigned int*)l, 16, 0, 0);
}

// Fused: L2-normalize row of S and T, quantize to e4m3 (x32), write packed
// fragment-major layout (via LDS so global writes are one contiguous 8 KB
// panel per matrix), and emit the diagonal correction term. (UNCHANGED)
__global__ __launch_bounds__(1024) void norm_quant_pack_kernel(
    const float* __restrict__ s_in, const float* __restrict__ t_in,
    unsigned char* __restrict__ sp, unsigned char* __restrict__ tp,
    float* __restrict__ corr) {
    __shared__ unsigned char pls[16384];  // [0,8192) S panel, [8192,16384) T
    const int wave = threadIdx.x >> 6;
    const int lane = threadIdx.x & 63;
    const int row = blockIdx.x * 16 + wave;
    const float4* s4 = (const float4*)(s_in + (size_t)row * D_DIM);
    const float4* t4 = (const float4*)(t_in + (size_t)row * D_DIM);
    float4 a0 = s4[lane * 2], a1 = s4[lane * 2 + 1];
    float4 b0 = t4[lane * 2], b1 = t4[lane * 2 + 1];
    float ss = a0.x * a0.x + a0.y * a0.y + a0.z * a0.z + a0.w * a0.w +
               a1.x * a1.x + a1.y * a1.y + a1.z * a1.z + a1.w * a1.w;
    float tt = b0.x * b0.x + b0.y * b0.y + b0.z * b0.z + b0.w * b0.w +
               b1.x * b1.x + b1.y * b1.y + b1.z * b1.z + b1.w * b1.w;
    float st = a0.x * b0.x + a0.y * b0.y + a0.z * b0.z + a0.w * b0.w +
               a1.x * b1.x + a1.y * b1.y + a1.z * b1.z + a1.w * b1.w;
#pragma unroll
    for (int off = 32; off > 0; off >>= 1) {
        ss += __shfl_down(ss, off);
        tt += __shfl_down(tt, off);
        st += __shfl_down(st, off);
    }
    ss = __shfl(ss, 0);
    tt = __shfl(tt, 0);
    const float ns = fmaxf(sqrtf(ss), 1e-12f);
    const float nt = fmaxf(sqrtf(tt), 1e-12f);
    if (lane == 0) {
        const float l = st / (ns * nt) * (1.0f / TEMPERATURE);
        corr[row] = softplus(-l - MARGIN) - softplus(l - MARGIN);
    }
    const float is = QSCALE / ns, it = QSCALE / nt;
    int s_lo = 0, s_hi = 0, t_lo = 0, t_hi = 0;
    s_lo = __builtin_amdgcn_cvt_pk_fp8_f32(a0.x * is, a0.y * is, s_lo, false);
    s_lo = __builtin_amdgcn_cvt_pk_fp8_f32(a0.z * is, a0.w * is, s_lo, true);
    s_hi = __builtin_amdgcn_cvt_pk_fp8_f32(a1.x * is, a1.y * is, s_hi, false);
    s_hi = __builtin_amdgcn_cvt_pk_fp8_f32(a1.z * is, a1.w * is, s_hi, true);
    t_lo = __builtin_amdgcn_cvt_pk_fp8_f32(b0.x * it, b0.y * it, t_lo, false);
    t_lo = __builtin_amdgcn_cvt_pk_fp8_f32(b0.z * it, b0.w * it, t_lo, true);
    t_hi = __builtin_amdgcn_cvt_pk_fp8_f32(b1.x * it, b1.y * it, t_hi, false);
    t_hi = __builtin_amdgcn_cvt_pk_fp8_f32(b1.z * it, b1.w * it, t_hi, true);
    const int local = (lane >> 4) * 2048 + ((lane >> 2) & 3) * 512 +
                      wave * 32 + (lane & 3) * 8;
    *(uint2*)(pls + local) = make_uint2((unsigned)s_lo, (unsigned)s_hi);
    *(uint2*)(pls + 8192 + local) = make_uint2((unsigned)t_lo, (unsigned)t_hi);
    __syncthreads();
    const int t = threadIdx.x;
    const size_t pbase = (size_t)blockIdx.x * 8192;
    *(uint2*)(sp + pbase + t * 8) = *(const uint2*)(pls + t * 8);
    *(uint2*)(tp + pbase + t * 8) = *(const uint2*)(pls + 8192 + t * 8);
}

// 128x256 logits tile per block; 4 waves 2x2, wave tile 64x128 = 2x4 of
// mfma_scale_f32_32x32x64_f8f6f4. Hybrid operand feed:
//   A: register-direct global loads (R1-proven path), double-buffered.
//   B: LDS-staged via global_load_lds (3 x 16 KB buffers, stage-ahead 2).
// 49 KB LDS + 256 threads -> 2 blocks/CU (cross-block overlap hides the
// per-block barrier). One s_barrier + one counted vmcnt per K-step.
__global__ __launch_bounds__(256, 2) void gemm_loss_kernel(
    const unsigned char* __restrict__ Sp, const unsigned char* __restrict__ Tp,
    float* __restrict__ partial) {
    __shared__ unsigned char lds[3 * 16384];
    __shared__ float wsums[4];

    const int tid = threadIdx.x;
    const int wave = tid >> 6;
    const int lane = tid & 63;
    const int wm = wave >> 1;   // 0..1 (M)
    const int wn = wave & 1;    // 0..1 (N)

    // XCD super-tile swizzle (grid 8192 = 128x64 tiles; 16x4-block super-tile
    // per XCD -> 1.5 MB of S+T panels L2-resident).
    const int b = blockIdx.x;
    const int xcd = b & 7;
    const int slot = b >> 3;
    const int sidx = slot >> 6;
    const int within = slot & 63;
    const int st_ = sidx * 8 + xcd;
    const int tm = (st_ >> 4) * 16 + (within >> 2);   // 0..127
    const int tn_ = (st_ & 15) * 4 + (within & 3);    // 0..63

    // ---- A register-direct addressing: wave's pairs = tm*4 + wm*2 + {0,1}
    const int laneoff =
        ((lane >> 4) & 1) * 8192 + (lane >> 5) * 512 + (lane & 15) * 32;
    const unsigned char* Ab =
        Sp + (size_t)(tm * 4 + wm * 2) * 16384 + laneoff;

    // ---- B staging: 16 chunks/K-step (16 panels), 4 per wave, 1024 B each.
    const int srcswz = (lane * 16) ^ ((lane & 0x38) << 1);
    const unsigned char* gb[4];
    int lo[4];
#pragma unroll
    for (int j = 0; j < 4; ++j) {
        const int c = wave * 4 + j;
        gb[j] = Tp + (size_t)(tn_ * 16 + c) * 8192 + srcswz;
        lo[j] = c * 1024;
    }

    // ---- B fragment read addressing (swizzled), within a 2048-B pair region
    const int fl =
        ((lane >> 4) & 1) * 1024 + (lane >> 5) * 512 + (lane & 15) * 32;
    const int s0 = fl ^ ((fl >> 3) & 0x70);
    const int boff = wn * 8192;  // wave's 4 pair-regions

    f32x16 acc[2][4];
#pragma unroll
    for (int pa = 0; pa < 2; ++pa)
#pragma unroll
        for (int pb = 0; pb < 4; ++pb)
#pragma unroll
            for (int r = 0; r < 16; ++r) acc[pa][pb][r] = 0.0f;

    v4i32 aL[2][4];  // [k-parity][pa*2 + half]: 4 explicit dwordx4 per step

    auto stage = [&](int buf, int ks) {
#pragma unroll
        for (int j = 0; j < 4; ++j)
            load_lds16(gb[j] + ks * 1024, &lds[buf * 16384 + lo[j]]);
    };
    auto loadA = [&](int p, int ks) {
#pragma unroll
        for (int pa = 0; pa < 2; ++pa) {
            aL[p][pa * 2] = *(const v4i32*)(Ab + pa * 16384 + ks * 1024);
            aL[p][pa * 2 + 1] =
                *(const v4i32*)(Ab + pa * 16384 + ks * 1024 + 16);
        }
    };

    // Prologue: queue = [st0(4), st1(4), A0(4)]; vmcnt(8) drains st0.
    stage(0, 0);
    stage(1, 1);
    loadA(0, 0);
    asm volatile("s_waitcnt vmcnt(8)" ::: "memory");
    __builtin_amdgcn_sched_barrier(0);
    __builtin_amdgcn_s_barrier();

#pragma unroll
    for (int ks = 0; ks < 8; ++ks) {
        // 1. stage-ahead (buffer (ks+2)%3 was fully read in step ks-1)
        if (ks + 2 < 8) stage((ks + 2) % 3, ks + 2);
        __builtin_amdgcn_sched_barrier(0);
        // 2. B fragment ds_reads from buf ks%3
        v8i32 bF[4];
        {
            const unsigned char* base = lds + (ks % 3) * 16384 + boff;
#pragma unroll
            for (int pb = 0; pb < 4; ++pb) {
                v4i32 l_ = *(const v4i32*)(base + pb * 2048 + s0);
                v4i32 h_ = *(const v4i32*)(base + pb * 2048 + (s0 ^ 16));
                bF[pb] =
                    __builtin_shufflevector(l_, h_, 0, 1, 2, 3, 4, 5, 6, 7);
            }
        }
        __builtin_amdgcn_sched_barrier(0);
        // 3. counted drain: [st(ks+1)4, A(ks)4, st(ks+2)4] -> keep st(ks+2)
        if (ks <= 5)
            asm volatile("s_waitcnt vmcnt(4)" ::: "memory");
        else
            asm volatile("s_waitcnt vmcnt(0)" ::: "memory");
        __builtin_amdgcn_sched_barrier(0);
        asm volatile("s_waitcnt lgkmcnt(0)" ::: "memory");
        __builtin_amdgcn_sched_barrier(0);
        // 4. MFMA cluster
        __builtin_amdgcn_s_setprio(1);
        {
            v8i32 aF[2];
#pragma unroll
            for (int pa = 0; pa < 2; ++pa)
                aF[pa] = __builtin_shufflevector(aL[ks & 1][pa * 2],
                                                 aL[ks & 1][pa * 2 + 1], 0, 1,
                                                 2, 3, 4, 5, 6, 7);
#pragma unroll
            for (int pb = 0; pb < 4; ++pb)
#pragma unroll
                for (int pa = 0; pa < 2; ++pa)
                    acc[pa][pb] =
                        __builtin_amdgcn_mfma_scale_f32_32x32x64_f8f6f4(
                            aF[pa], bF[pb], acc[pa][pb], 0 /*cbsz*/,
                            0 /*blgp*/, 0, SCALE_BYTE, 0, SCALE_BYTE);
        }
        __builtin_amdgcn_s_setprio(0);
        __builtin_amdgcn_sched_barrier(0);
        // 5. A-ahead (issue after MFMA so vmcnt ordering holds)
        if (ks + 1 < 8) loadA((ks + 1) & 1, ks + 1);
        __builtin_amdgcn_sched_barrier(0);
        // 6. barrier: st(ks+1) already drained by step-ks vmcnt
        if (ks < 7) __builtin_amdgcn_s_barrier();
    }

    // Uniform epilogue: sum softplus(logit - margin) over all elems.
    // softplus(z) = ln2*( (y+|y|)/2 + log2(1+2^(-|y|)) ), y = z*log2e;
    // log2 terms folded into one v_log per 16-elem group via a product.
    const float C1 = (1.0f / TEMPERATURE) * 1.4426950408889634f;  // log2e/T
    const float C2 = -MARGIN * 1.4426950408889634f;
    float ysum = 0.0f, asum = 0.0f, lsum = 0.0f;
#pragma unroll
    for (int pa = 0; pa < 2; ++pa)
#pragma unroll
        for (int pb = 0; pb < 4; ++pb) {
            float prod = 1.0f;
#pragma unroll
            for (int r = 0; r < 16; ++r) {
                const float y = fmaf(acc[pa][pb][r], C1, C2);
                ysum += y;
                const float ay = fabsf(y);
                asum += ay;
                prod = fmaf(prod, __builtin_amdgcn_exp2f(-ay), prod);
            }
            lsum += __builtin_amdgcn_logf(prod);
        }
    float total =
        fmaf(ysum + asum, 0.5f, lsum) * 0.6931471805599453f;  // * ln2
#pragma unroll
    for (int off = 32; off > 0; off >>= 1) total += __shfl_down(total, off);
    if (lane == 0) wsums[wave] = total;
    __syncthreads();
    if (tid == 0)
        partial[b] = wsums[0] + wsums[1] + wsums[2] + wsums[3];
}

__global__ __launch_bounds__(256) void reduce_kernel(
    const float* __restrict__ partial, int nPartials,
    const float* __restrict__ corr, int nCorr, int N,
    float* __restrict__ out) {
    float s = 0.0f;
    for (int i = threadIdx.x; i < nPartials; i += 256) s += partial[i];
    for (int i = threadIdx.x; i < nCorr; i += 256) s += corr[i];
#pragma unroll
    for (int off = 32; off > 0; off >>= 1) s += __shfl_down(s, off);
    __shared__ float ws[4];
    const int wave = threadIdx.x >> 6;
    const int lane = threadIdx.x & 63;
    if (lane == 0) ws[wave] = s;
    __syncthreads();
    if (threadIdx.x == 0) out[0] = (ws[0] + ws[1] + ws[2] + ws[3]) / (float)N;
}

extern "C" void kernel_launch(void* const* d_in, const int* in_sizes, int n_in,
                              void* d_out, int out_size, void* d_ws, size_t ws_size,
                              hipStream_t stream) {
    (void)n_in; (void)out_size; (void)ws_size;
    const float* s_in = (const float*)d_in[0];
    const float* t_in = (const float*)d_in[1];
    const int N = in_sizes[0] / D_DIM;  // 16384

    unsigned char* sp = (unsigned char*)d_ws;                    // N*512 fp8 packed
    unsigned char* tp = sp + (size_t)N * D_DIM;                  // N*512 fp8 packed
    float* partial = (float*)(tp + (size_t)N * D_DIM);           // 8192 floats
    const int nPartials = (N / BM) * (N / BN);
    float* corr = partial + nPartials;                           // N floats

    norm_quant_pack_kernel<<<N / 16, 1024, 0, stream>>>(s_in, t_in, sp, tp,
                                                        corr);
    gemm_loss_kernel<<<nPartials, 256, 0, stream>>>(sp, tp, partial);
    reduce_kernel<<<1, 256, 0, stream>>>(partial, nPartials, corr, N, N,
                                         (float*)d_out);
}

// Round 4
// 238.849 us; speedup vs baseline: 1.1995x; 1.1213x over previous
//
#include <hip/hip_runtime.h>
#include <stdint.h>

#define TEMPERATURE 0.07f
#define MARGIN 0.1f
#define D_DIM 512          // elements per row
#define BM 128
#define BN 256
#define QSCALE 32.0f       // pre-quantization scale (2^5)
#define SCALE_BYTE 0x7A7A7A7A  // e8m0 2^-5 replicated (compensates QSCALE^2)

// Packed fragment-major layout (per matrix, N*512 bytes):
//   elem [row][k] -> (row>>4)*8192 + (k>>5)*512 + (row&15)*32 + (k&31)
// Panel = 16 rows (8192 B); pair-region = 2 panels (16384 B) = 32 rows.
// mfma_scale_f32_32x32x64_f8f6f4 lane-L fragment of a pair at kstep ks:
//   global: pair*16384 + ((L>>4)&1)*8192 + (L>>5)*512 + (L&15)*32 + ks*1024
// LDS-staged B buffers use the involution
//   f(d) = d ^ ((d>>3)&0x70) ^ ((d>>5)&0x30)
// (slot index bits 4-6 XORed with row bits 7-10) so that every 8-lane
// phase of a ds_read_b128 hits 8 distinct 16-B slots AND the four 16-lane
// groups (which differ only in bits 9-10) get distinct slot patterns.
// Applied on the global SOURCE side of global_load_lds (dest stays linear)
// and on the ds_read address.

typedef int v8i32 __attribute__((ext_vector_type(8)));
typedef int v4i32 __attribute__((ext_vector_type(4)));
typedef float f32x16 __attribute__((ext_vector_type(16)));

__device__ __forceinline__ float softplus(float x) {
    return fmaxf(x, 0.0f) + __logf(1.0f + __expf(-fabsf(x)));
}

__device__ __forceinline__ void load_lds16(const unsigned char* g,
                                           unsigned char* l) {
    __builtin_amdgcn_global_load_lds(
        (const __attribute__((address_space(1))) unsigned int*)g,
        (__attribute__((address_space(3))) unsigned int*)l, 16, 0, 0);
}

// Fused: L2-normalize row of S and T, quantize to e4m3 (x32), write packed
// fragment-major layout (via LDS so global writes are one contiguous 8 KB
// panel per matrix), and emit a per-block (16-row) reduced corr term.
__global__ __launch_bounds__(1024) void norm_quant_pack_kernel(
    const float* __restrict__ s_in, const float* __restrict__ t_in,
    unsigned char* __restrict__ sp, unsigned char* __restrict__ tp,
    float* __restrict__ corrb) {
    __shared__ unsigned char pls[16384];  // [0,8192) S panel, [8192,16384) T
    __shared__ float cshr[16];
    const int wave = threadIdx.x >> 6;
    const int lane = threadIdx.x & 63;
    const int row = blockIdx.x * 16 + wave;
    const float4* s4 = (const float4*)(s_in + (size_t)row * D_DIM);
    const float4* t4 = (const float4*)(t_in + (size_t)row * D_DIM);
    float4 a0 = s4[lane * 2], a1 = s4[lane * 2 + 1];
    float4 b0 = t4[lane * 2], b1 = t4[lane * 2 + 1];
    float ss = a0.x * a0.x + a0.y * a0.y + a0.z * a0.z + a0.w * a0.w +
               a1.x * a1.x + a1.y * a1.y + a1.z * a1.z + a1.w * a1.w;
    float tt = b0.x * b0.x + b0.y * b0.y + b0.z * b0.z + b0.w * b0.w +
               b1.x * b1.x + b1.y * b1.y + b1.z * b1.z + b1.w * b1.w;
    float st = a0.x * b0.x + a0.y * b0.y + a0.z * b0.z + a0.w * b0.w +
               a1.x * b1.x + a1.y * b1.y + a1.z * b1.z + a1.w * b1.w;
#pragma unroll
    for (int off = 32; off > 0; off >>= 1) {
        ss += __shfl_down(ss, off);
        tt += __shfl_down(tt, off);
        st += __shfl_down(st, off);
    }
    ss = __shfl(ss, 0);
    tt = __shfl(tt, 0);
    const float ns = fmaxf(sqrtf(ss), 1e-12f);
    const float nt = fmaxf(sqrtf(tt), 1e-12f);
    if (lane == 0) {
        const float l = st / (ns * nt) * (1.0f / TEMPERATURE);
        cshr[wave] = softplus(-l - MARGIN) - softplus(l - MARGIN);
    }
    const float is = QSCALE / ns, it = QSCALE / nt;
    int s_lo = 0, s_hi = 0, t_lo = 0, t_hi = 0;
    s_lo = __builtin_amdgcn_cvt_pk_fp8_f32(a0.x * is, a0.y * is, s_lo, false);
    s_lo = __builtin_amdgcn_cvt_pk_fp8_f32(a0.z * is, a0.w * is, s_lo, true);
    s_hi = __builtin_amdgcn_cvt_pk_fp8_f32(a1.x * is, a1.y * is, s_hi, false);
    s_hi = __builtin_amdgcn_cvt_pk_fp8_f32(a1.z * is, a1.w * is, s_hi, true);
    t_lo = __builtin_amdgcn_cvt_pk_fp8_f32(b0.x * it, b0.y * it, t_lo, false);
    t_lo = __builtin_amdgcn_cvt_pk_fp8_f32(b0.z * it, b0.w * it, t_lo, true);
    t_hi = __builtin_amdgcn_cvt_pk_fp8_f32(b1.x * it, b1.y * it, t_hi, false);
    t_hi = __builtin_amdgcn_cvt_pk_fp8_f32(b1.z * it, b1.w * it, t_hi, true);
    const int local = (lane >> 4) * 2048 + ((lane >> 2) & 3) * 512 +
                      wave * 32 + (lane & 3) * 8;
    *(uint2*)(pls + local) = make_uint2((unsigned)s_lo, (unsigned)s_hi);
    *(uint2*)(pls + 8192 + local) = make_uint2((unsigned)t_lo, (unsigned)t_hi);
    __syncthreads();
    const int t = threadIdx.x;
    const size_t pbase = (size_t)blockIdx.x * 8192;
    *(uint2*)(sp + pbase + t * 8) = *(const uint2*)(pls + t * 8);
    *(uint2*)(tp + pbase + t * 8) = *(const uint2*)(pls + 8192 + t * 8);
    if (t == 0) {
        float c = 0.0f;
#pragma unroll
        for (int w = 0; w < 16; ++w) c += cshr[w];
        corrb[blockIdx.x] = c;
    }
}

// 128x256 logits tile per block; 4 waves 2x2, wave tile 64x128 = 2x4 of
// mfma_scale_f32_32x32x64_f8f6f4. Hybrid operand feed:
//   A: register-direct global loads, double-buffered (one K-step ahead).
//   B: LDS-staged via global_load_lds (3 x 16 KB buffers, stage-ahead 2).
// NO manual waitcnt in the loop: issue order is pinned (ds_reads -> stage
// -> loadA) and the compiler's position-accurate counted waits both
// interleave ds_read completion with the MFMA clusters (lgkmcnt(6/4/2/0))
// and drain each stage buffer before the barrier (the aL-use vmcnt is
// older-inclusive). One raw s_barrier per K-step.
__global__ __launch_bounds__(256, 2) void gemm_loss_kernel(
    const unsigned char* __restrict__ Sp, const unsigned char* __restrict__ Tp,
    float* __restrict__ partial) {
    __shared__ unsigned char lds[3 * 16384];
    __shared__ float wsums[4];

    const int tid = threadIdx.x;
    const int wave = tid >> 6;
    const int lane = tid & 63;
    const int wm = wave >> 1;   // 0..1 (M)
    const int wn = wave & 1;    // 0..1 (N)

    // XCD super-tile swizzle (grid 8192 = 128x64 tiles; 16x4-block super-tile
    // per XCD -> 1.5 MB of S+T panels L2-resident).
    const int b = blockIdx.x;
    const int xcd = b & 7;
    const int slot = b >> 3;
    const int sidx = slot >> 6;
    const int within = slot & 63;
    const int st_ = sidx * 8 + xcd;
    const int tm = (st_ >> 4) * 16 + (within >> 2);   // 0..127
    const int tn_ = (st_ & 15) * 4 + (within & 3);    // 0..63

    // ---- A register-direct addressing: wave's pairs = tm*4 + wm*2 + {0,1}
    const int laneoff =
        ((lane >> 4) & 1) * 8192 + (lane >> 5) * 512 + (lane & 15) * 32;
    const unsigned char* Ab =
        Sp + (size_t)(tm * 4 + wm * 2) * 16384 + laneoff;

    // ---- B staging: 16 chunks/K-step (16 panels), 4 per wave, 1024 B each.
    // Source pre-swizzle = f applied to (c*1024 + lane*16):
    //   (lane*16) ^ ((lane&0x38)<<1) ^ ((lane>>1)&0x10) ^ ((c&1)<<5)
    const int sbase =
        (lane * 16) ^ ((lane & 0x38) << 1) ^ ((lane >> 1) & 0x10);
    const unsigned char* gb[4];
    int lo[4];
#pragma unroll
    for (int j = 0; j < 4; ++j) {
        const int c = wave * 4 + j;
        gb[j] = Tp + (size_t)(tn_ * 16 + c) * 8192 + (sbase ^ ((c & 1) << 5));
        lo[j] = c * 1024;
    }

    // ---- B fragment read addressing: region-local orig addr fl, swizzled
    const int fl =
        ((lane >> 4) & 1) * 1024 + (lane >> 5) * 512 + (lane & 15) * 32;
    const int s0 = fl ^ ((fl >> 3) & 0x70) ^ ((fl >> 5) & 0x30);
    const int boff = wn * 8192;  // wave's 4 pair-regions

    f32x16 acc[2][4];
#pragma unroll
    for (int pa = 0; pa < 2; ++pa)
#pragma unroll
        for (int pb = 0; pb < 4; ++pb)
#pragma unroll
            for (int r = 0; r < 16; ++r) acc[pa][pb][r] = 0.0f;

    v4i32 aL[2][4];  // [k-parity][pa*2 + half]: 4 explicit dwordx4 per step

    auto stage = [&](int buf, int ks) {
#pragma unroll
        for (int j = 0; j < 4; ++j)
            load_lds16(gb[j] + ks * 1024, &lds[buf * 16384 + lo[j]]);
    };
    auto loadA = [&](int p, int ks) {
#pragma unroll
        for (int pa = 0; pa < 2; ++pa) {
            aL[p][pa * 2] = *(const v4i32*)(Ab + pa * 16384 + ks * 1024);
            aL[p][pa * 2 + 1] =
                *(const v4i32*)(Ab + pa * 16384 + ks * 1024 + 16);
        }
    };

    // Prologue: queue = [st0(4), st1(4), A0(4)]; vmcnt(8) drains st0 only.
    stage(0, 0);
    stage(1, 1);
    loadA(0, 0);
    asm volatile("s_waitcnt vmcnt(8)" ::: "memory");
    __builtin_amdgcn_sched_barrier(0);
    __builtin_amdgcn_s_barrier();

#pragma unroll
    for (int ks = 0; ks < 8; ++ks) {
        // 1. issue this step's B fragment reads (buf ks%3), in pb order
        const unsigned char* base = lds + (ks % 3) * 16384 + boff;
        v8i32 bF[4];
#pragma unroll
        for (int pb = 0; pb < 4; ++pb) {
            v4i32 l_ = *(const v4i32*)(base + pb * 2048 + s0);
            v4i32 h_ = *(const v4i32*)(base + pb * 2048 + (s0 ^ 16));
            bF[pb] = __builtin_shufflevector(l_, h_, 0, 1, 2, 3, 4, 5, 6, 7);
        }
        __builtin_amdgcn_sched_barrier(0);
        // 2. stage-ahead (buffer (ks+2)%3 was fully read at step ks-1),
        //    then A-ahead. Order matters: the compiler's wait for aL(ks)
        //    (issued last step, before st(ks+1)... i.e. older) drains
        //    st(ks+1) before the end-of-step barrier.
        if (ks + 2 < 8) stage((ks + 2) % 3, ks + 2);
        __builtin_amdgcn_sched_barrier(0);
        if (ks + 1 < 8) loadA((ks + 1) & 1, ks + 1);
        __builtin_amdgcn_sched_barrier(0);
        // 3. MFMA clusters; compiler inserts counted lgkm/vm waits per use
        __builtin_amdgcn_s_setprio(1);
        {
            v8i32 aF[2];
#pragma unroll
            for (int pa = 0; pa < 2; ++pa)
                aF[pa] = __builtin_shufflevector(aL[ks & 1][pa * 2],
                                                 aL[ks & 1][pa * 2 + 1], 0, 1,
                                                 2, 3, 4, 5, 6, 7);
#pragma unroll
            for (int pb = 0; pb < 4; ++pb)
#pragma unroll
                for (int pa = 0; pa < 2; ++pa)
                    acc[pa][pb] =
                        __builtin_amdgcn_mfma_scale_f32_32x32x64_f8f6f4(
                            aF[pa], bF[pb], acc[pa][pb], 0 /*cbsz*/,
                            0 /*blgp*/, 0, SCALE_BYTE, 0, SCALE_BYTE);
        }
        __builtin_amdgcn_s_setprio(0);
        __builtin_amdgcn_sched_barrier(0);
        // 4. step boundary
        if (ks < 7) __builtin_amdgcn_s_barrier();
    }

    // Uniform epilogue: sum softplus(logit - margin) over all elems.
    // softplus(z) = ln2*( (y+|y|)/2 + log2(1+2^(-|y|)) ), y = z*log2e;
    // log2 terms folded into one v_log per 16-elem group via a product.
    const float C1 = (1.0f / TEMPERATURE) * 1.4426950408889634f;  // log2e/T
    const float C2 = -MARGIN * 1.4426950408889634f;
    float ysum = 0.0f, asum = 0.0f, lsum = 0.0f;
#pragma unroll
    for (int pa = 0; pa < 2; ++pa)
#pragma unroll
        for (int pb = 0; pb < 4; ++pb) {
            float prod = 1.0f;
#pragma unroll
            for (int r = 0; r < 16; ++r) {
                const float y = fmaf(acc[pa][pb][r], C1, C2);
                ysum += y;
                const float ay = fabsf(y);
                asum += ay;
                prod = fmaf(prod, __builtin_amdgcn_exp2f(-ay), prod);
            }
            lsum += __builtin_amdgcn_logf(prod);
        }
    float total =
        fmaf(ysum + asum, 0.5f, lsum) * 0.6931471805599453f;  // * ln2
#pragma unroll
    for (int off = 32; off > 0; off >>= 1) total += __shfl_down(total, off);
    if (lane == 0) wsums[wave] = total;
    __syncthreads();
    if (tid == 0)
        partial[b] = wsums[0] + wsums[1] + wsums[2] + wsums[3];
}

__global__ __launch_bounds__(256) void reduce_kernel(
    const float* __restrict__ partial, int nPartials,
    const float* __restrict__ corr, int nCorr, int N,
    float* __restrict__ out) {
    const float4* p4 = (const float4*)partial;
    const float4* c4 = (const float4*)corr;
    float sx = 0.0f, sy = 0.0f, sz = 0.0f, sw = 0.0f;
    for (int i = threadIdx.x; i < nPartials / 4; i += 256) {
        float4 v = p4[i];
        sx += v.x; sy += v.y; sz += v.z; sw += v.w;
    }
    for (int i = threadIdx.x; i < nCorr / 4; i += 256) {
        float4 v = c4[i];
        sx += v.x; sy += v.y; sz += v.z; sw += v.w;
    }
    float s = (sx + sy) + (sz + sw);
#pragma unroll
    for (int off = 32; off > 0; off >>= 1) s += __shfl_down(s, off);
    __shared__ float ws[4];
    const int wave = threadIdx.x >> 6;
    const int lane = threadIdx.x & 63;
    if (lane == 0) ws[wave] = s;
    __syncthreads();
    if (threadIdx.x == 0) out[0] = (ws[0] + ws[1] + ws[2] + ws[3]) / (float)N;
}

extern "C" void kernel_launch(void* const* d_in, const int* in_sizes, int n_in,
                              void* d_out, int out_size, void* d_ws, size_t ws_size,
                              hipStream_t stream) {
    (void)n_in; (void)out_size; (void)ws_size;
    const float* s_in = (const float*)d_in[0];
    const float* t_in = (const float*)d_in[1];
    const int N = in_sizes[0] / D_DIM;  // 16384

    unsigned char* sp = (unsigned char*)d_ws;                    // N*512 fp8 packed
    unsigned char* tp = sp + (size_t)N * D_DIM;                  // N*512 fp8 packed
    float* partial = (float*)(tp + (size_t)N * D_DIM);           // 8192 floats
    const int nPartials = (N / BM) * (N / BN);
    float* corrb = partial + nPartials;                          // N/16 floats
    const int nCorr = N / 16;

    norm_quant_pack_kernel<<<N / 16, 1024, 0, stream>>>(s_in, t_in, sp, tp,
                                                        corrb);
    gemm_loss_kernel<<<nPartials, 256, 0, stream>>>(sp, tp, partial);
    reduce_kernel<<<1, 256, 0, stream>>>(partial, nPartials, corrb, nCorr, N,
                                         (float*)d_out);
}

// Round 5
// 238.828 us; speedup vs baseline: 1.1996x; 1.0001x over previous
//
#include <hip/hip_runtime.h>
#include <stdint.h>

#define TEMPERATURE 0.07f
#define MARGIN 0.1f
#define D_DIM 512          // elements per row
#define BM 128
#define BN 256
#define QSCALE 32.0f       // pre-quantization scale (2^5)
#define SCALE_BYTE 0x7A7A7A7A  // e8m0 2^-5 replicated (compensates QSCALE^2)

// Packed fragment-major layout (per matrix, N*512 bytes):
//   elem [row][k] -> (row>>4)*8192 + (k>>5)*512 + (row&15)*32 + (k&31)
// Panel = 16 rows (8192 B); pair-region = 2 panels (16384 B) = 32 rows.
// mfma_scale_f32_32x32x64_f8f6f4 lane-L fragment of a pair at kstep ks:
//   global: pair*16384 + ((L>>4)&1)*8192 + (L>>5)*512 + (L&15)*32 + ks*1024
// LDS-staged B buffers use the involution
//   f(d) = d ^ ((d>>3)&0x70) ^ ((d>>5)&0x30)
// applied on the global SOURCE side of global_load_lds (dest stays linear)
// and on the ds_read address. (Residual SQ_LDS_BANK_CONFLICT of 4 cy per
// ds_read_b128 is the intrinsic b128 cost — swizzle-invariant, measured.)

typedef int v8i32 __attribute__((ext_vector_type(8)));
typedef int v4i32 __attribute__((ext_vector_type(4)));
typedef float f32x16 __attribute__((ext_vector_type(16)));

__device__ __forceinline__ float softplus(float x) {
    return fmaxf(x, 0.0f) + __logf(1.0f + __expf(-fabsf(x)));
}

__device__ __forceinline__ void load_lds16(const unsigned char* g,
                                           unsigned char* l) {
    __builtin_amdgcn_global_load_lds(
        (const __attribute__((address_space(1))) unsigned int*)g,
        (__attribute__((address_space(3))) unsigned int*)l, 16, 0, 0);
}

// Fused: L2-normalize row of S and T, quantize to e4m3 (x32), write packed
// fragment-major layout (via LDS so global writes are one contiguous 8 KB
// panel per matrix), and emit a per-block (16-row) reduced corr term.
__global__ __launch_bounds__(1024) void norm_quant_pack_kernel(
    const float* __restrict__ s_in, const float* __restrict__ t_in,
    unsigned char* __restrict__ sp, unsigned char* __restrict__ tp,
    float* __restrict__ corrb) {
    __shared__ unsigned char pls[16384];  // [0,8192) S panel, [8192,16384) T
    __shared__ float cshr[16];
    const int wave = threadIdx.x >> 6;
    const int lane = threadIdx.x & 63;
    const int row = blockIdx.x * 16 + wave;
    const float4* s4 = (const float4*)(s_in + (size_t)row * D_DIM);
    const float4* t4 = (const float4*)(t_in + (size_t)row * D_DIM);
    float4 a0 = s4[lane * 2], a1 = s4[lane * 2 + 1];
    float4 b0 = t4[lane * 2], b1 = t4[lane * 2 + 1];
    float ss = a0.x * a0.x + a0.y * a0.y + a0.z * a0.z + a0.w * a0.w +
               a1.x * a1.x + a1.y * a1.y + a1.z * a1.z + a1.w * a1.w;
    float tt = b0.x * b0.x + b0.y * b0.y + b0.z * b0.z + b0.w * b0.w +
               b1.x * b1.x + b1.y * b1.y + b1.z * b1.z + b1.w * b1.w;
    float st = a0.x * b0.x + a0.y * b0.y + a0.z * b0.z + a0.w * b0.w +
               a1.x * b1.x + a1.y * b1.y + a1.z * b1.z + a1.w * b1.w;
#pragma unroll
    for (int off = 32; off > 0; off >>= 1) {
        ss += __shfl_down(ss, off);
        tt += __shfl_down(tt, off);
        st += __shfl_down(st, off);
    }
    ss = __shfl(ss, 0);
    tt = __shfl(tt, 0);
    const float ns = fmaxf(sqrtf(ss), 1e-12f);
    const float nt = fmaxf(sqrtf(tt), 1e-12f);
    if (lane == 0) {
        const float l = st / (ns * nt) * (1.0f / TEMPERATURE);
        cshr[wave] = softplus(-l - MARGIN) - softplus(l - MARGIN);
    }
    const float is = QSCALE / ns, it = QSCALE / nt;
    int s_lo = 0, s_hi = 0, t_lo = 0, t_hi = 0;
    s_lo = __builtin_amdgcn_cvt_pk_fp8_f32(a0.x * is, a0.y * is, s_lo, false);
    s_lo = __builtin_amdgcn_cvt_pk_fp8_f32(a0.z * is, a0.w * is, s_lo, true);
    s_hi = __builtin_amdgcn_cvt_pk_fp8_f32(a1.x * is, a1.y * is, s_hi, false);
    s_hi = __builtin_amdgcn_cvt_pk_fp8_f32(a1.z * is, a1.w * is, s_hi, true);
    t_lo = __builtin_amdgcn_cvt_pk_fp8_f32(b0.x * it, b0.y * it, t_lo, false);
    t_lo = __builtin_amdgcn_cvt_pk_fp8_f32(b0.z * it, b0.w * it, t_lo, true);
    t_hi = __builtin_amdgcn_cvt_pk_fp8_f32(b1.x * it, b1.y * it, t_hi, false);
    t_hi = __builtin_amdgcn_cvt_pk_fp8_f32(b1.z * it, b1.w * it, t_hi, true);
    const int local = (lane >> 4) * 2048 + ((lane >> 2) & 3) * 512 +
                      wave * 32 + (lane & 3) * 8;
    *(uint2*)(pls + local) = make_uint2((unsigned)s_lo, (unsigned)s_hi);
    *(uint2*)(pls + 8192 + local) = make_uint2((unsigned)t_lo, (unsigned)t_hi);
    __syncthreads();
    const int t = threadIdx.x;
    const size_t pbase = (size_t)blockIdx.x * 8192;
    *(uint2*)(sp + pbase + t * 8) = *(const uint2*)(pls + t * 8);
    *(uint2*)(tp + pbase + t * 8) = *(const uint2*)(pls + 8192 + t * 8);
    if (t == 0) {
        float c = 0.0f;
#pragma unroll
        for (int w = 0; w < 16; ++w) c += cshr[w];
        corrb[blockIdx.x] = c;
    }
}

// 128x256 logits tile per block; 4 waves 2x2, wave tile 64x128 = 2x4 of
// mfma_scale_f32_32x32x64_f8f6f4. Hybrid operand feed:
//   A: register-direct global loads, double-buffered (one K-step ahead).
//   B: LDS-staged via global_load_lds (4 x 16 KB buffers).
// K-steps merged into 2-step INTERVALS: one s_barrier + one manual counted
// vmcnt(4) per interval (4 barriers total, never a drain-to-0 mid-loop).
// Drain ledger per interval i (steps a=2i, b=2i+1), per wave:
//   MFMA(a) auto-wait (for loadA(a)) drains stage(a+1) [older]
//   MFMA(b) auto-wait (for loadA(b)) drains stage(2i+2) [older]
//   manual vmcnt(4) drains stage(2i+3), keeps loadA(2i+2) in flight
//   s_barrier => all waves' DMA for bufs {2i+2,2i+3} visible next interval.
__global__ __launch_bounds__(256, 2) void gemm_loss_kernel(
    const unsigned char* __restrict__ Sp, const unsigned char* __restrict__ Tp,
    float* __restrict__ partial) {
    __shared__ unsigned char lds[4 * 16384];
    __shared__ float wsums[4];

    const int tid = threadIdx.x;
    const int wave = tid >> 6;
    const int lane = tid & 63;
    const int wm = wave >> 1;   // 0..1 (M)
    const int wn = wave & 1;    // 0..1 (N)

    // XCD super-tile swizzle (grid 8192 = 128x64 tiles; 16x4-block super-tile
    // per XCD -> 1.5 MB of S+T panels L2-resident).
    const int b = blockIdx.x;
    const int xcd = b & 7;
    const int slot = b >> 3;
    const int sidx = slot >> 6;
    const int within = slot & 63;
    const int st_ = sidx * 8 + xcd;
    const int tm = (st_ >> 4) * 16 + (within >> 2);   // 0..127
    const int tn_ = (st_ & 15) * 4 + (within & 3);    // 0..63

    // ---- A register-direct addressing: wave's pairs = tm*4 + wm*2 + {0,1}
    const int laneoff =
        ((lane >> 4) & 1) * 8192 + (lane >> 5) * 512 + (lane & 15) * 32;
    const unsigned char* Ab =
        Sp + (size_t)(tm * 4 + wm * 2) * 16384 + laneoff;

    // ---- B staging: 16 chunks/K-step (16 panels), 4 per wave, 1024 B each.
    const int sbase =
        (lane * 16) ^ ((lane & 0x38) << 1) ^ ((lane >> 1) & 0x10);
    const unsigned char* gb[4];
    int lo[4];
#pragma unroll
    for (int j = 0; j < 4; ++j) {
        const int c = wave * 4 + j;
        gb[j] = Tp + (size_t)(tn_ * 16 + c) * 8192 + (sbase ^ ((c & 1) << 5));
        lo[j] = c * 1024;
    }

    // ---- B fragment read addressing: region-local orig addr fl, swizzled
    const int fl =
        ((lane >> 4) & 1) * 1024 + (lane >> 5) * 512 + (lane & 15) * 32;
    const int s0 = fl ^ ((fl >> 3) & 0x70) ^ ((fl >> 5) & 0x30);
    const int boff = wn * 8192;  // wave's 4 pair-regions

    f32x16 acc[2][4];
#pragma unroll
    for (int pa = 0; pa < 2; ++pa)
#pragma unroll
        for (int pb = 0; pb < 4; ++pb)
#pragma unroll
            for (int r = 0; r < 16; ++r) acc[pa][pb][r] = 0.0f;

    v4i32 aL[2][4];  // [k-parity][pa*2 + half]: 4 explicit dwordx4 per step

    auto stage = [&](int buf, int ks) {
#pragma unroll
        for (int j = 0; j < 4; ++j)
            load_lds16(gb[j] + ks * 1024, &lds[buf * 16384 + lo[j]]);
    };
    auto loadA = [&](int p, int ks) {
#pragma unroll
        for (int pa = 0; pa < 2; ++pa) {
            aL[p][pa * 2] = *(const v4i32*)(Ab + pa * 16384 + ks * 1024);
            aL[p][pa * 2 + 1] =
                *(const v4i32*)(Ab + pa * 16384 + ks * 1024 + 16);
        }
    };
    auto readsBF = [&](int ks, v8i32(&bF)[4]) {
        const unsigned char* base = lds + (ks & 3) * 16384 + boff;
#pragma unroll
        for (int pb = 0; pb < 4; ++pb) {
            v4i32 l_ = *(const v4i32*)(base + pb * 2048 + s0);
            v4i32 h_ = *(const v4i32*)(base + pb * 2048 + (s0 ^ 16));
            bF[pb] = __builtin_shufflevector(l_, h_, 0, 1, 2, 3, 4, 5, 6, 7);
        }
    };
    auto mfma8 = [&](int p, v8i32(&bF)[4]) {
        __builtin_amdgcn_s_setprio(1);
        v8i32 aF[2];
#pragma unroll
        for (int pa = 0; pa < 2; ++pa)
            aF[pa] = __builtin_shufflevector(aL[p][pa * 2], aL[p][pa * 2 + 1],
                                             0, 1, 2, 3, 4, 5, 6, 7);
#pragma unroll
        for (int pb = 0; pb < 4; ++pb)
#pragma unroll
            for (int pa = 0; pa < 2; ++pa)
                acc[pa][pb] = __builtin_amdgcn_mfma_scale_f32_32x32x64_f8f6f4(
                    aF[pa], bF[pb], acc[pa][pb], 0 /*cbsz*/, 0 /*blgp*/,
                    0, SCALE_BYTE, 0, SCALE_BYTE);
        __builtin_amdgcn_s_setprio(0);
    };

#define SB __builtin_amdgcn_sched_barrier(0)

    // Prologue: [st0(4), st1(4), A0(4)] -> vmcnt(4) drains st0 AND st1
    // (both bufs read this interval, cross-wave), keeps A0 in flight.
    stage(0, 0);
    stage(1, 1);
    loadA(0, 0);
    SB;
    asm volatile("s_waitcnt vmcnt(4)" ::: "memory");
    SB;
    __builtin_amdgcn_s_barrier();
    SB;

#pragma unroll
    for (int iv = 0; iv < 4; ++iv) {
        const int ksA = 2 * iv, ksB = 2 * iv + 1;
        v8i32 bF[4];
        // ---- step A
        readsBF(ksA, bF);
        if (ksA + 2 < 8) stage((ksA + 2) & 3, ksA + 2);
        SB;                      // stage before loadA (drain ledger)
        loadA(1, ksB);
        SB;                      // loadA before MFMA issue
        mfma8(0, bF);            // auto-wait drains loadA(ksA)+stage(ksA+1)
        SB;                      // stepB reads must not hoist above drain
        // ---- step B
        readsBF(ksB, bF);
        if (ksB + 2 < 8) stage((ksB + 2) & 3, ksB + 2);
        SB;
        if (ksB + 1 < 8) loadA(0, ksB + 1);
        SB;
        mfma8(1, bF);            // auto-wait drains loadA(ksB)+stage(2iv+2)
        SB;
        if (iv < 3) {
            asm volatile("s_waitcnt vmcnt(4)" ::: "memory");  // drain stage(2iv+3)
            SB;
            __builtin_amdgcn_s_barrier();
            SB;
        }
    }
#undef SB

    // Uniform epilogue: sum softplus(logit - margin) over all elems.
    // softplus(z) = ln2*( (y+|y|)/2 + log2(1+2^(-|y|)) ), y = z*log2e;
    // log2 terms folded into one v_log per 16-elem group via a product.
    const float C1 = (1.0f / TEMPERATURE) * 1.4426950408889634f;  // log2e/T
    const float C2 = -MARGIN * 1.4426950408889634f;
    float ysum = 0.0f, asum = 0.0f, lsum = 0.0f;
#pragma unroll
    for (int pa = 0; pa < 2; ++pa)
#pragma unroll
        for (int pb = 0; pb < 4; ++pb) {
            float prod = 1.0f;
#pragma unroll
            for (int r = 0; r < 16; ++r) {
                const float y = fmaf(acc[pa][pb][r], C1, C2);
                ysum += y;
                const float ay = fabsf(y);
                asum += ay;
                prod = fmaf(prod, __builtin_amdgcn_exp2f(-ay), prod);
            }
            lsum += __builtin_amdgcn_logf(prod);
        }
    float total =
        fmaf(ysum + asum, 0.5f, lsum) * 0.6931471805599453f;  // * ln2
#pragma unroll
    for (int off = 32; off > 0; off >>= 1) total += __shfl_down(total, off);
    if (lane == 0) wsums[wave] = total;
    __syncthreads();
    if (tid == 0)
        partial[b] = wsums[0] + wsums[1] + wsums[2] + wsums[3];
}

__global__ __launch_bounds__(256) void reduce_kernel(
    const float* __restrict__ partial, int nPartials,
    const float* __restrict__ corr, int nCorr, int N,
    float* __restrict__ out) {
    const float4* p4 = (const float4*)partial;
    const float4* c4 = (const float4*)corr;
    float sx = 0.0f, sy = 0.0f, sz = 0.0f, sw = 0.0f;
    for (int i = threadIdx.x; i < nPartials / 4; i += 256) {
        float4 v = p4[i];
        sx += v.x; sy += v.y; sz += v.z; sw += v.w;
    }
    for (int i = threadIdx.x; i < nCorr / 4; i += 256) {
        float4 v = c4[i];
        sx += v.x; sy += v.y; sz += v.z; sw += v.w;
    }
    float s = (sx + sy) + (sz + sw);
#pragma unroll
    for (int off = 32; off > 0; off >>= 1) s += __shfl_down(s, off);
    __shared__ float ws[4];
    const int wave = threadIdx.x >> 6;
    const int lane = threadIdx.x & 63;
    if (lane == 0) ws[wave] = s;
    __syncthreads();
    if (threadIdx.x == 0) out[0] = (ws[0] + ws[1] + ws[2] + ws[3]) / (float)N;
}

extern "C" void kernel_launch(void* const* d_in, const int* in_sizes, int n_in,
                              void* d_out, int out_size, void* d_ws, size_t ws_size,
                              hipStream_t stream) {
    (void)n_in; (void)out_size; (void)ws_size;
    const float* s_in = (const float*)d_in[0];
    const float* t_in = (const float*)d_in[1];
    const int N = in_sizes[0] / D_DIM;  // 16384

    unsigned char* sp = (unsigned char*)d_ws;                    // N*512 fp8 packed
    unsigned char* tp = sp + (size_t)N * D_DIM;                  // N*512 fp8 packed
    float* partial = (float*)(tp + (size_t)N * D_DIM);           // 8192 floats
    const int nPartials = (N / BM) * (N / BN);
    float* corrb = partial + nPartials;                          // N/16 floats
    const int nCorr = N / 16;

    norm_quant_pack_kernel<<<N / 16, 1024, 0, stream>>>(s_in, t_in, sp, tp,
                                                        corrb);
    gemm_loss_kernel<<<nPartials, 256, 0, stream>>>(sp, tp, partial);
    reduce_kernel<<<1, 256, 0, stream>>>(partial, nPartials, corrb, nCorr, N,
                                         (float*)d_out);
}

// Round 6
// 234.695 us; speedup vs baseline: 1.2207x; 1.0176x over previous
//
#include <hip/hip_runtime.h>
#include <stdint.h>

#define TEMPERATURE 0.07f
#define MARGIN 0.1f
#define D_DIM 512          // elements per row
#define BM 128
#define BN 256
#define QSCALE 32.0f       // pre-quantization scale (2^5)
#define SCALE_BYTE 0x7A7A7A7A  // e8m0 2^-5 replicated (compensates QSCALE^2)

// Packed fragment-major layout (per matrix, N*512 bytes):
//   elem [row][k] -> (row>>4)*8192 + (k>>5)*512 + (row&15)*32 + (k&31)
// Panel = 16 rows (8192 B); pair-region = 2 panels (16384 B) = 32 rows.
// mfma_scale_f32_32x32x64_f8f6f4 lane-L fragment of a pair at kstep ks:
//   global: pair*16384 + ((L>>4)&1)*8192 + (L>>5)*512 + (L&15)*32 + ks*1024
// LDS-staged B buffers use the involution
//   f(d) = d ^ ((d>>3)&0x70) ^ ((d>>5)&0x30)
// applied on the global SOURCE side of global_load_lds (dest stays linear)
// and on the ds_read address. (Residual SQ_LDS_BANK_CONFLICT of 4 cy per
// ds_read_b128 is the intrinsic b128 cost — swizzle-invariant, measured.)

typedef int v8i32 __attribute__((ext_vector_type(8)));
typedef int v4i32 __attribute__((ext_vector_type(4)));
typedef float f32x16 __attribute__((ext_vector_type(16)));

__device__ __forceinline__ float softplus(float x) {
    return fmaxf(x, 0.0f) + __logf(1.0f + __expf(-fabsf(x)));
}

__device__ __forceinline__ void load_lds16(const unsigned char* g,
                                           unsigned char* l) {
    __builtin_amdgcn_global_load_lds(
        (const __attribute__((address_space(1))) unsigned int*)g,
        (__attribute__((address_space(3))) unsigned int*)l, 16, 0, 0);
}

// Fused: L2-normalize row of S and T, quantize to e4m3 (x32), write packed
// fragment-major layout (via LDS so global writes are one contiguous 8 KB
// panel per matrix), and emit a per-block (16-row) reduced corr term.
__global__ __launch_bounds__(1024) void norm_quant_pack_kernel(
    const float* __restrict__ s_in, const float* __restrict__ t_in,
    unsigned char* __restrict__ sp, unsigned char* __restrict__ tp,
    float* __restrict__ corrb) {
    __shared__ unsigned char pls[16384];  // [0,8192) S panel, [8192,16384) T
    __shared__ float cshr[16];
    const int wave = threadIdx.x >> 6;
    const int lane = threadIdx.x & 63;
    const int row = blockIdx.x * 16 + wave;
    const float4* s4 = (const float4*)(s_in + (size_t)row * D_DIM);
    const float4* t4 = (const float4*)(t_in + (size_t)row * D_DIM);
    float4 a0 = s4[lane * 2], a1 = s4[lane * 2 + 1];
    float4 b0 = t4[lane * 2], b1 = t4[lane * 2 + 1];
    float ss = a0.x * a0.x + a0.y * a0.y + a0.z * a0.z + a0.w * a0.w +
               a1.x * a1.x + a1.y * a1.y + a1.z * a1.z + a1.w * a1.w;
    float tt = b0.x * b0.x + b0.y * b0.y + b0.z * b0.z + b0.w * b0.w +
               b1.x * b1.x + b1.y * b1.y + b1.z * b1.z + b1.w * b1.w;
    float st = a0.x * b0.x + a0.y * b0.y + a0.z * b0.z + a0.w * b0.w +
               a1.x * b1.x + a1.y * b1.y + a1.z * b1.z + a1.w * b1.w;
#pragma unroll
    for (int off = 32; off > 0; off >>= 1) {
        ss += __shfl_down(ss, off);
        tt += __shfl_down(tt, off);
        st += __shfl_down(st, off);
    }
    ss = __shfl(ss, 0);
    tt = __shfl(tt, 0);
    const float ns = fmaxf(sqrtf(ss), 1e-12f);
    const float nt = fmaxf(sqrtf(tt), 1e-12f);
    if (lane == 0) {
        const float l = st / (ns * nt) * (1.0f / TEMPERATURE);
        cshr[wave] = softplus(-l - MARGIN) - softplus(l - MARGIN);
    }
    const float is = QSCALE / ns, it = QSCALE / nt;
    int s_lo = 0, s_hi = 0, t_lo = 0, t_hi = 0;
    s_lo = __builtin_amdgcn_cvt_pk_fp8_f32(a0.x * is, a0.y * is, s_lo, false);
    s_lo = __builtin_amdgcn_cvt_pk_fp8_f32(a0.z * is, a0.w * is, s_lo, true);
    s_hi = __builtin_amdgcn_cvt_pk_fp8_f32(a1.x * is, a1.y * is, s_hi, false);
    s_hi = __builtin_amdgcn_cvt_pk_fp8_f32(a1.z * is, a1.w * is, s_hi, true);
    t_lo = __builtin_amdgcn_cvt_pk_fp8_f32(b0.x * it, b0.y * it, t_lo, false);
    t_lo = __builtin_amdgcn_cvt_pk_fp8_f32(b0.z * it, b0.w * it, t_lo, true);
    t_hi = __builtin_amdgcn_cvt_pk_fp8_f32(b1.x * it, b1.y * it, t_hi, false);
    t_hi = __builtin_amdgcn_cvt_pk_fp8_f32(b1.z * it, b1.w * it, t_hi, true);
    const int local = (lane >> 4) * 2048 + ((lane >> 2) & 3) * 512 +
                      wave * 32 + (lane & 3) * 8;
    *(uint2*)(pls + local) = make_uint2((unsigned)s_lo, (unsigned)s_hi);
    *(uint2*)(pls + 8192 + local) = make_uint2((unsigned)t_lo, (unsigned)t_hi);
    __syncthreads();
    const int t = threadIdx.x;
    const size_t pbase = (size_t)blockIdx.x * 8192;
    *(uint2*)(sp + pbase + t * 8) = *(const uint2*)(pls + t * 8);
    *(uint2*)(tp + pbase + t * 8) = *(const uint2*)(pls + 8192 + t * 8);
    if (t == 0) {
        float c = 0.0f;
#pragma unroll
        for (int w = 0; w < 16; ++w) c += cshr[w];
        corrb[blockIdx.x] = c;
    }
}

// 128x256 logits tile per block; 4 waves 2x2, wave tile 64x128 = 2x4 of
// mfma_scale_f32_32x32x64_f8f6f4. Hybrid operand feed:
//   A: register-direct global loads, double-buffered (one K-step ahead).
//   B: LDS-staged via global_load_lds (4 x 16 KB buffers).
// 2-step intervals, one s_barrier + one counted vmcnt(4) per interval.
// WITHIN each step: pair-granular software pipeline — ds_read pair p+1
// issued between the MFMA pairs of p (per-pair counted lgkm waits), and
// the stage/loadA VMEM blocks issued mid-step so the TA port, LDS pipe
// and matrix pipe run CONCURRENTLY. sched_barrier(0) only where the
// vmcnt drain ledger requires issue-order (stage block vs loadA block
// vs interval-end vmcnt); everything else is left to the scheduler.
// Drain ledger per interval i (steps a=2i, b=2i+1), per wave:
//   stepB first MFMA auto-wait (for loadA(b)) drains stage(2i+2) [older]
//   manual vmcnt(4) drains stage(2i+3), keeps loadA(2i+2) in flight
//   s_barrier => all waves' DMA for bufs {2i+2,2i+3} visible next interval.
__global__ __launch_bounds__(256, 2) void gemm_loss_kernel(
    const unsigned char* __restrict__ Sp, const unsigned char* __restrict__ Tp,
    float* __restrict__ partial) {
    __shared__ unsigned char lds[4 * 16384];
    __shared__ float wsums[4];

    const int tid = threadIdx.x;
    const int wave = tid >> 6;
    const int lane = tid & 63;
    const int wm = wave >> 1;   // 0..1 (M)
    const int wn = wave & 1;    // 0..1 (N)

    // XCD super-tile swizzle (grid 8192 = 128x64 tiles; 16x4-block super-tile
    // per XCD -> 1.5 MB of S+T panels L2-resident).
    const int b = blockIdx.x;
    const int xcd = b & 7;
    const int slot = b >> 3;
    const int sidx = slot >> 6;
    const int within = slot & 63;
    const int st_ = sidx * 8 + xcd;
    const int tm = (st_ >> 4) * 16 + (within >> 2);   // 0..127
    const int tn_ = (st_ & 15) * 4 + (within & 3);    // 0..63

    // ---- A register-direct addressing: wave's pairs = tm*4 + wm*2 + {0,1}
    const int laneoff =
        ((lane >> 4) & 1) * 8192 + (lane >> 5) * 512 + (lane & 15) * 32;
    const unsigned char* Ab =
        Sp + (size_t)(tm * 4 + wm * 2) * 16384 + laneoff;

    // ---- B staging: 16 chunks/K-step (16 panels), 4 per wave, 1024 B each.
    const int sbase =
        (lane * 16) ^ ((lane & 0x38) << 1) ^ ((lane >> 1) & 0x10);
    const unsigned char* gb[4];
    int lo[4];
#pragma unroll
    for (int j = 0; j < 4; ++j) {
        const int c = wave * 4 + j;
        gb[j] = Tp + (size_t)(tn_ * 16 + c) * 8192 + (sbase ^ ((c & 1) << 5));
        lo[j] = c * 1024;
    }

    // ---- B fragment read addressing: region-local orig addr fl, swizzled
    const int fl =
        ((lane >> 4) & 1) * 1024 + (lane >> 5) * 512 + (lane & 15) * 32;
    const int s0 = fl ^ ((fl >> 3) & 0x70) ^ ((fl >> 5) & 0x30);
    const int boff = wn * 8192;  // wave's 4 pair-regions

    f32x16 acc[2][4];
#pragma unroll
    for (int pa = 0; pa < 2; ++pa)
#pragma unroll
        for (int pb = 0; pb < 4; ++pb)
#pragma unroll
            for (int r = 0; r < 16; ++r) acc[pa][pb][r] = 0.0f;

    v4i32 aL[2][4];  // [k-parity][pa*2 + half]: 4 explicit dwordx4 per step

    auto stage = [&](int buf, int ks) {
#pragma unroll
        for (int j = 0; j < 4; ++j)
            load_lds16(gb[j] + ks * 1024, &lds[buf * 16384 + lo[j]]);
    };
    auto loadA = [&](int p, int ks) {
#pragma unroll
        for (int pa = 0; pa < 2; ++pa) {
            aL[p][pa * 2] = *(const v4i32*)(Ab + pa * 16384 + ks * 1024);
            aL[p][pa * 2 + 1] =
                *(const v4i32*)(Ab + pa * 16384 + ks * 1024 + 16);
        }
    };
    auto readB = [&](int ks, int pb) -> v8i32 {
        const unsigned char* base = lds + (ks & 3) * 16384 + boff + pb * 2048;
        v4i32 l_ = *(const v4i32*)(base + s0);
        v4i32 h_ = *(const v4i32*)(base + (s0 ^ 16));
        return __builtin_shufflevector(l_, h_, 0, 1, 2, 3, 4, 5, 6, 7);
    };
    auto mfma2 = [&](int pb, v8i32 bf, int p) {
        __builtin_amdgcn_s_setprio(1);
        v8i32 aF0 = __builtin_shufflevector(aL[p][0], aL[p][1], 0, 1, 2, 3, 4,
                                            5, 6, 7);
        v8i32 aF1 = __builtin_shufflevector(aL[p][2], aL[p][3], 0, 1, 2, 3, 4,
                                            5, 6, 7);
        acc[0][pb] = __builtin_amdgcn_mfma_scale_f32_32x32x64_f8f6f4(
            aF0, bf, acc[0][pb], 0, 0, 0, SCALE_BYTE, 0, SCALE_BYTE);
        acc[1][pb] = __builtin_amdgcn_mfma_scale_f32_32x32x64_f8f6f4(
            aF1, bf, acc[1][pb], 0, 0, 0, SCALE_BYTE, 0, SCALE_BYTE);
        __builtin_amdgcn_s_setprio(0);
    };

#define SB __builtin_amdgcn_sched_barrier(0)

    // Prologue: [st0(4), st1(4), A0(4)] -> vmcnt(4) drains st0 AND st1,
    // keeps A0 in flight.
    stage(0, 0);
    SB;
    stage(1, 1);
    SB;
    loadA(0, 0);
    SB;
    asm volatile("s_waitcnt vmcnt(4)" ::: "memory");
    SB;
    __builtin_amdgcn_s_barrier();
    SB;

#pragma unroll
    for (int iv = 0; iv < 4; ++iv) {
        const int ksA = 2 * iv, ksB = 2 * iv + 1;
        // ---- step A (parity 0): pair-pipelined reads + mid-step VMEM
        {
            v8i32 b0 = readB(ksA, 0);
            v8i32 b1 = readB(ksA, 1);
            mfma2(0, b0, 0);
            v8i32 b2 = readB(ksA, 2);
            mfma2(1, b1, 0);
            v8i32 b3 = readB(ksA, 3);
            if (ksA + 2 < 8) stage((ksA + 2) & 3, ksA + 2);
            SB;  // ledger: stage(2iv+2) fully issued before loadA(ksB)
            loadA(1, ksB);
            SB;  // ledger: loadA(ksB) after stage block
            mfma2(2, b2, 0);
            mfma2(3, b3, 0);
        }
        // ---- step B (parity 1); first mfma2 auto-wait (aL[1]) drains
        // stage(2iv+2)
        {
            v8i32 b0 = readB(ksB, 0);
            v8i32 b1 = readB(ksB, 1);
            mfma2(0, b0, 1);
            v8i32 b2 = readB(ksB, 2);
            mfma2(1, b1, 1);
            v8i32 b3 = readB(ksB, 3);
            if (ksB + 2 < 8) stage((ksB + 2) & 3, ksB + 2);
            SB;  // ledger: stage(2iv+3) fully issued before loadA(2iv+2)
            if (ksB + 1 < 8) loadA(0, ksB + 1);
            SB;  // ledger: loadA(2iv+2) last in the VMEM queue
            mfma2(2, b2, 1);
            mfma2(3, b3, 1);
        }
        if (iv < 3) {
            SB;
            asm volatile("s_waitcnt vmcnt(4)" ::: "memory");
            SB;
            __builtin_amdgcn_s_barrier();
            SB;
        }
    }
#undef SB

    // Uniform epilogue: sum softplus(logit - margin) over all elems.
    // softplus(z) = ln2*( (y+|y|)/2 + log2(1+2^(-|y|)) ), y = z*log2e;
    // log2 terms folded into one v_log per 16-elem group via a product.
    const float C1 = (1.0f / TEMPERATURE) * 1.4426950408889634f;  // log2e/T
    const float C2 = -MARGIN * 1.4426950408889634f;
    float ysum = 0.0f, asum = 0.0f, lsum = 0.0f;
#pragma unroll
    for (int pa = 0; pa < 2; ++pa)
#pragma unroll
        for (int pb = 0; pb < 4; ++pb) {
            float prod = 1.0f;
#pragma unroll
            for (int r = 0; r < 16; ++r) {
                const float y = fmaf(acc[pa][pb][r], C1, C2);
                ysum += y;
                const float ay = fabsf(y);
                asum += ay;
                prod = fmaf(prod, __builtin_amdgcn_exp2f(-ay), prod);
            }
            lsum += __builtin_amdgcn_logf(prod);
        }
    float total =
        fmaf(ysum + asum, 0.5f, lsum) * 0.6931471805599453f;  // * ln2
#pragma unroll
    for (int off = 32; off > 0; off >>= 1) total += __shfl_down(total, off);
    if (lane == 0) wsums[wave] = total;
    __syncthreads();
    if (tid == 0)
        partial[b] = wsums[0] + wsums[1] + wsums[2] + wsums[3];
}

__global__ __launch_bounds__(256) void reduce_kernel(
    const float* __restrict__ partial, int nPartials,
    const float* __restrict__ corr, int nCorr, int N,
    float* __restrict__ out) {
    const float4* p4 = (const float4*)partial;
    const float4* c4 = (const float4*)corr;
    float sx = 0.0f, sy = 0.0f, sz = 0.0f, sw = 0.0f;
    for (int i = threadIdx.x; i < nPartials / 4; i += 256) {
        float4 v = p4[i];
        sx += v.x; sy += v.y; sz += v.z; sw += v.w;
    }
    for (int i = threadIdx.x; i < nCorr / 4; i += 256) {
        float4 v = c4[i];
        sx += v.x; sy += v.y; sz += v.z; sw += v.w;
    }
    float s = (sx + sy) + (sz + sw);
#pragma unroll
    for (int off = 32; off > 0; off >>= 1) s += __shfl_down(s, off);
    __shared__ float ws[4];
    const int wave = threadIdx.x >> 6;
    const int lane = threadIdx.x & 63;
    if (lane == 0) ws[wave] = s;
    __syncthreads();
    if (threadIdx.x == 0) out[0] = (ws[0] + ws[1] + ws[2] + ws[3]) / (float)N;
}

extern "C" void kernel_launch(void* const* d_in, const int* in_sizes, int n_in,
                              void* d_out, int out_size, void* d_ws, size_t ws_size,
                              hipStream_t stream) {
    (void)n_in; (void)out_size; (void)ws_size;
    const float* s_in = (const float*)d_in[0];
    const float* t_in = (const float*)d_in[1];
    const int N = in_sizes[0] / D_DIM;  // 16384

    unsigned char* sp = (unsigned char*)d_ws;                    // N*512 fp8 packed
    unsigned char* tp = sp + (size_t)N * D_DIM;                  // N*512 fp8 packed
    float* partial = (float*)(tp + (size_t)N * D_DIM);           // 8192 floats
    const int nPartials = (N / BM) * (N / BN);
    float* corrb = partial + nPartials;                          // N/16 floats
    const int nCorr = N / 16;

    norm_quant_pack_kernel<<<N / 16, 1024, 0, stream>>>(s_in, t_in, sp, tp,
                                                        corrb);
    gemm_loss_kernel<<<nPartials, 256, 0, stream>>>(sp, tp, partial);
    reduce_kernel<<<1, 256, 0, stream>>>(partial, nPartials, corrb, nCorr, N,
                                         (float*)d_out);
}

// Round 7
// 196.593 us; speedup vs baseline: 1.4573x; 1.1938x over previous
//
#include <hip/hip_runtime.h>
#include <stdint.h>

#define TEMPERATURE 0.07f
#define MARGIN 0.1f
#define D_DIM 512          // elements per row
#define BM 128
#define BN 256
#define QSCALE 32.0f       // pre-quantization scale (2^5)
#define SCALE_BYTE 0x7A7A7A7A  // e8m0 2^-5 replicated (compensates QSCALE^2)
#define KS_STRIDE 524288   // bytes per K-step slab: 1024 panels * 512 B

// FP4 (e2m1) packed layout, ks-major (per matrix, N*256 bytes = 4 MB):
//   nibble(row,k) -> byte  (k>>6)*KS_STRIDE + (row>>4)*512
//                        + ((k>>5)&1)*256 + (row&15)*16 + ((k&31)>>1)
//   (k even = low nibble; within-lane k order is irrelevant: both operands
//    use the identical packing, so any k permutation cancels in the dot.)
// mfma_scale_f32_32x32x64_f8f6f4 (cbsz=blgp=4 -> FP4) lane-L fragment of a
// panel-pair at kstep ks: 16 B at
//   ks*KS_STRIDE + (2*pair + ((L>>4)&1))*512 + (L>>5)*256 + (L&15)*16
// A wave's pair-read covers its 1024-B region exactly once -> bank-conflict
// floor; LDS staging and reads are fully LINEAR (no swizzle).

typedef int v8i32 __attribute__((ext_vector_type(8)));
typedef int v4i32 __attribute__((ext_vector_type(4)));
typedef float f32x16 __attribute__((ext_vector_type(16)));

__device__ __forceinline__ float softplus(float x) {
    return fmaxf(x, 0.0f) + __logf(1.0f + __expf(-fabsf(x)));
}

// e2m1 round-to-nearest encode. Levels: 0,.5,1,1.5,2,3,4,6 (codes 0..7).
__device__ __forceinline__ unsigned enc_fp4(float v) {
    const float ay = fabsf(v);
    int c = 0;
    c += ay > 0.25f;
    c += ay > 0.75f;
    c += ay > 1.25f;
    c += ay > 1.75f;
    c += ay > 2.5f;
    c += ay > 3.5f;
    c += ay > 5.0f;
    return (unsigned)c | ((__float_as_uint(v) >> 28) & 8u);
}

__device__ __forceinline__ void load_lds16(const unsigned char* g,
                                           unsigned char* l) {
    __builtin_amdgcn_global_load_lds(
        (const __attribute__((address_space(1))) unsigned int*)g,
        (__attribute__((address_space(3))) unsigned int*)l, 16, 0, 0);
}

// Fused: L2-normalize row of S and T, quantize to e2m1 fp4 (x32), write the
// ks-major packed layout (via LDS so global writes are 512-B contiguous
// pieces), and emit a per-block (16-row) reduced corr term.
__global__ __launch_bounds__(1024) void norm_quant_pack_kernel(
    const float* __restrict__ s_in, const float* __restrict__ t_in,
    unsigned char* __restrict__ sp, unsigned char* __restrict__ tp,
    float* __restrict__ corrb) {
    __shared__ unsigned pls[2048];  // words: [0,1024) S panel, [1024,2048) T
    __shared__ float cshr[16];
    const int wave = threadIdx.x >> 6;
    const int lane = threadIdx.x & 63;
    const int row = blockIdx.x * 16 + wave;
    const float4* s4 = (const float4*)(s_in + (size_t)row * D_DIM);
    const float4* t4 = (const float4*)(t_in + (size_t)row * D_DIM);
    float4 a0 = s4[lane * 2], a1 = s4[lane * 2 + 1];
    float4 b0 = t4[lane * 2], b1 = t4[lane * 2 + 1];
    float ss = a0.x * a0.x + a0.y * a0.y + a0.z * a0.z + a0.w * a0.w +
               a1.x * a1.x + a1.y * a1.y + a1.z * a1.z + a1.w * a1.w;
    float tt = b0.x * b0.x + b0.y * b0.y + b0.z * b0.z + b0.w * b0.w +
               b1.x * b1.x + b1.y * b1.y + b1.z * b1.z + b1.w * b1.w;
    float st = a0.x * b0.x + a0.y * b0.y + a0.z * b0.z + a0.w * b0.w +
               a1.x * b1.x + a1.y * b1.y + a1.z * b1.z + a1.w * b1.w;
#pragma unroll
    for (int off = 32; off > 0; off >>= 1) {
        ss += __shfl_down(ss, off);
        tt += __shfl_down(tt, off);
        st += __shfl_down(st, off);
    }
    ss = __shfl(ss, 0);
    tt = __shfl(tt, 0);
    const float ns = fmaxf(sqrtf(ss), 1e-12f);
    const float nt = fmaxf(sqrtf(tt), 1e-12f);
    if (lane == 0) {
        const float l = st / (ns * nt) * (1.0f / TEMPERATURE);
        cshr[wave] = softplus(-l - MARGIN) - softplus(l - MARGIN);
    }
    const float is = QSCALE / ns, it = QSCALE / nt;
    // 8 elems (k = 8*lane .. 8*lane+7) -> one u32 of nibbles, k ascending.
    const unsigned ws_ = enc_fp4(a0.x * is) | (enc_fp4(a0.y * is) << 4) |
                         (enc_fp4(a0.z * is) << 8) | (enc_fp4(a0.w * is) << 12) |
                         (enc_fp4(a1.x * is) << 16) | (enc_fp4(a1.y * is) << 20) |
                         (enc_fp4(a1.z * is) << 24) | (enc_fp4(a1.w * is) << 28);
    const unsigned wt_ = enc_fp4(b0.x * it) | (enc_fp4(b0.y * it) << 4) |
                         (enc_fp4(b0.z * it) << 8) | (enc_fp4(b0.w * it) << 12) |
                         (enc_fp4(b1.x * it) << 16) | (enc_fp4(b1.y * it) << 20) |
                         (enc_fp4(b1.z * it) << 24) | (enc_fp4(b1.w * it) << 28);
    // word index: ks(=lane>>3)*128 + khalf(=(lane>>2)&1)*64 + row*4 + (lane&3)
    const int widx =
        (lane >> 3) * 128 + ((lane >> 2) & 1) * 64 + wave * 4 + (lane & 3);
    pls[widx] = ws_;
    pls[1024 + widx] = wt_;
    __syncthreads();
    const int t = threadIdx.x;
    const int ks = t >> 7, rem = t & 127;
    const size_t goff = (size_t)ks * KS_STRIDE + (size_t)blockIdx.x * 512 +
                        (size_t)rem * 4;
    *(unsigned*)(sp + goff) = pls[t];
    *(unsigned*)(tp + goff) = pls[1024 + t];
    if (t == 0) {
        float c = 0.0f;
#pragma unroll
        for (int w = 0; w < 16; ++w) c += cshr[w];
        corrb[blockIdx.x] = c;
    }
}

// 128x256 logits tile per block; 4 waves 2x2, wave tile 64x128 = 2x4 of
// FP4 mfma_scale_f32_32x32x64_f8f6f4 (cbsz=blgp=4). Hybrid operand feed:
//   A: register-direct global loads (2 x dwordx4/step), double-buffered.
//   B: LDS-staged via global_load_lds (4 x 8 KB buffers, fully linear:
//      per K-step the 16 B-panels are one contiguous 8 KB slab).
// 2-step intervals, one s_barrier + one counted vmcnt(2) per interval.
// Drain ledger per interval i (steps a=2i, b=2i+1), per wave (stage=2,
// loadA=2 VMEM ops):
//   MFMA(a) auto-wait (aL[0]=loadA(a))  : oldest, keeps st(2i+2), A(b)
//   MFMA(b) auto-wait (aL[1]=loadA(b))  : drains st(2i+2)
//   manual vmcnt(2)                     : drains st(2i+3), keeps A(2i+2)
//   s_barrier => bufs {2i+2, 2i+3} visible to all waves next interval.
__global__ __launch_bounds__(256, 2) void gemm_loss_kernel(
    const unsigned char* __restrict__ Sp, const unsigned char* __restrict__ Tp,
    float* __restrict__ partial) {
    __shared__ unsigned char lds[4 * 8192];
    __shared__ float wsums[4];

    const int tid = threadIdx.x;
    const int wave = tid >> 6;
    const int lane = tid & 63;
    const int wm = wave >> 1;   // 0..1 (M)
    const int wn = wave & 1;    // 0..1 (N)

    // XCD super-tile swizzle (grid 8192 = 128x64 tiles; 16x4-block super-tile
    // per XCD -> S+T panels L2-resident).
    const int b = blockIdx.x;
    const int xcd = b & 7;
    const int slot = b >> 3;
    const int sidx = slot >> 6;
    const int within = slot & 63;
    const int st_ = sidx * 8 + xcd;
    const int tm = (st_ >> 4) * 16 + (within >> 2);   // 0..127
    const int tn_ = (st_ & 15) * 4 + (within & 3);    // 0..63

    // Per-lane fp4 fragment offset within a pair-region (1024 B)
    const int fl4 =
        ((lane >> 4) & 1) * 512 + (lane >> 5) * 256 + (lane & 15) * 16;

    // ---- A register-direct: wave's pairs = tm*4 + wm*2 + {0,1};
    //      pair stride 1024 B, K-step stride KS_STRIDE.
    const unsigned char* Ab = Sp + (size_t)(tm * 4 + wm * 2) * 1024 + fl4;

    // ---- B staging: 8 KB contiguous per K-step, 2 x 1 KB chunks per wave.
    const unsigned char* Bg =
        Tp + (size_t)tn_ * 8192 + (wave * 2) * 1024 + lane * 16;
    const int lo0 = wave * 2 * 1024;
    const int boff = wn * 4096;  // wave's 4 pair-regions in the buffer

    f32x16 acc[2][4];
#pragma unroll
    for (int pa = 0; pa < 2; ++pa)
#pragma unroll
        for (int pb = 0; pb < 4; ++pb)
#pragma unroll
            for (int r = 0; r < 16; ++r) acc[pa][pb][r] = 0.0f;

    v4i32 aL[2][2];  // [k-parity][pa]: 2 dwordx4 per step

    auto stage = [&](int buf, int ks) {
        const unsigned char* g = Bg + (size_t)ks * KS_STRIDE;
        load_lds16(g, &lds[buf * 8192 + lo0]);
        load_lds16(g + 1024, &lds[buf * 8192 + lo0 + 1024]);
    };
    auto loadA = [&](int p, int ks) {
        const unsigned char* g = Ab + (size_t)ks * KS_STRIDE;
        aL[p][0] = *(const v4i32*)(g);
        aL[p][1] = *(const v4i32*)(g + 1024);
    };
    auto readB = [&](int ks, int pb) -> v8i32 {
        v4i32 l_ = *(const v4i32*)(lds + (ks & 3) * 8192 + boff + pb * 1024 + fl4);
        return __builtin_shufflevector(l_, l_, 0, 1, 2, 3, 0, 1, 2, 3);
    };
    auto mfma8 = [&](int p, v8i32(&bF)[4]) {
        __builtin_amdgcn_s_setprio(1);
        v8i32 aF0 = __builtin_shufflevector(aL[p][0], aL[p][0], 0, 1, 2, 3, 0,
                                            1, 2, 3);
        v8i32 aF1 = __builtin_shufflevector(aL[p][1], aL[p][1], 0, 1, 2, 3, 0,
                                            1, 2, 3);
#pragma unroll
        for (int pb = 0; pb < 4; ++pb) {
            acc[0][pb] = __builtin_amdgcn_mfma_scale_f32_32x32x64_f8f6f4(
                aF0, bF[pb], acc[0][pb], 4 /*fp4*/, 4 /*fp4*/,
                0, SCALE_BYTE, 0, SCALE_BYTE);
            acc[1][pb] = __builtin_amdgcn_mfma_scale_f32_32x32x64_f8f6f4(
                aF1, bF[pb], acc[1][pb], 4 /*fp4*/, 4 /*fp4*/,
                0, SCALE_BYTE, 0, SCALE_BYTE);
        }
        __builtin_amdgcn_s_setprio(0);
    };

#define SB __builtin_amdgcn_sched_barrier(0)

    // Prologue: [st0(2), st1(2), A0(2)] -> vmcnt(2) drains st0+st1, keeps A0.
    stage(0, 0);
    SB;
    stage(1, 1);
    SB;
    loadA(0, 0);
    SB;
    asm volatile("s_waitcnt vmcnt(2)" ::: "memory");
    SB;
    __builtin_amdgcn_s_barrier();
    SB;

#pragma unroll
    for (int iv = 0; iv < 4; ++iv) {
        const int ksA = 2 * iv, ksB = 2 * iv + 1;
        // ---- step A (parity 0)
        {
            v8i32 bF[4];
#pragma unroll
            for (int pb = 0; pb < 4; ++pb) bF[pb] = readB(ksA, pb);
            if (ksA + 2 < 8) stage((ksA + 2) & 3, ksA + 2);
            SB;  // ledger: stage(2iv+2) issued before loadA(ksB)
            loadA(1, ksB);
            SB;  // ledger: loadA(ksB) after the stage block
            mfma8(0, bF);
        }
        // ---- step B (parity 1); first MFMA auto-wait drains stage(2iv+2)
        {
            v8i32 bF[4];
#pragma unroll
            for (int pb = 0; pb < 4; ++pb) bF[pb] = readB(ksB, pb);
            if (ksB + 2 < 8) stage((ksB + 2) & 3, ksB + 2);
            SB;  // ledger: stage(2iv+3) issued before loadA(2iv+2)
            if (ksB + 1 < 8) loadA(0, ksB + 1);
            SB;  // ledger: loadA(2iv+2) last in the VMEM queue
            mfma8(1, bF);
        }
        if (iv < 3) {
            SB;
            asm volatile("s_waitcnt vmcnt(2)" ::: "memory");
            SB;
            __builtin_amdgcn_s_barrier();
            SB;
        }
    }
#undef SB

    // Uniform epilogue: sum softplus(logit - margin) over all elems.
    // softplus(z) = ln2*( (y+|y|)/2 + log2(1+2^(-|y|)) ), y = z*log2e;
    // log2 terms folded into one v_log per 16-elem group via a product.
    const float C1 = (1.0f / TEMPERATURE) * 1.4426950408889634f;  // log2e/T
    const float C2 = -MARGIN * 1.4426950408889634f;
    float ysum = 0.0f, asum = 0.0f, lsum = 0.0f;
#pragma unroll
    for (int pa = 0; pa < 2; ++pa)
#pragma unroll
        for (int pb = 0; pb < 4; ++pb) {
            float prod = 1.0f;
#pragma unroll
            for (int r = 0; r < 16; ++r) {
                const float y = fmaf(acc[pa][pb][r], C1, C2);
                ysum += y;
                const float ay = fabsf(y);
                asum += ay;
                prod = fmaf(prod, __builtin_amdgcn_exp2f(-ay), prod);
            }
            lsum += __builtin_amdgcn_logf(prod);
        }
    float total =
        fmaf(ysum + asum, 0.5f, lsum) * 0.6931471805599453f;  // * ln2
#pragma unroll
    for (int off = 32; off > 0; off >>= 1) total += __shfl_down(total, off);
    if (lane == 0) wsums[wave] = total;
    __syncthreads();
    if (tid == 0)
        partial[b] = wsums[0] + wsums[1] + wsums[2] + wsums[3];
}

__global__ __launch_bounds__(256) void reduce_kernel(
    const float* __restrict__ partial, int nPartials,
    const float* __restrict__ corr, int nCorr, int N,
    float* __restrict__ out) {
    const float4* p4 = (const float4*)partial;
    const float4* c4 = (const float4*)corr;
    float sx = 0.0f, sy = 0.0f, sz = 0.0f, sw = 0.0f;
    for (int i = threadIdx.x; i < nPartials / 4; i += 256) {
        float4 v = p4[i];
        sx += v.x; sy += v.y; sz += v.z; sw += v.w;
    }
    for (int i = threadIdx.x; i < nCorr / 4; i += 256) {
        float4 v = c4[i];
        sx += v.x; sy += v.y; sz += v.z; sw += v.w;
    }
    float s = (sx + sy) + (sz + sw);
#pragma unroll
    for (int off = 32; off > 0; off >>= 1) s += __shfl_down(s, off);
    __shared__ float ws[4];
    const int wave = threadIdx.x >> 6;
    const int lane = threadIdx.x & 63;
    if (lane == 0) ws[wave] = s;
    __syncthreads();
    if (threadIdx.x == 0) out[0] = (ws[0] + ws[1] + ws[2] + ws[3]) / (float)N;
}

extern "C" void kernel_launch(void* const* d_in, const int* in_sizes, int n_in,
                              void* d_out, int out_size, void* d_ws, size_t ws_size,
                              hipStream_t stream) {
    (void)n_in; (void)out_size; (void)ws_size;
    const float* s_in = (const float*)d_in[0];
    const float* t_in = (const float*)d_in[1];
    const int N = in_sizes[0] / D_DIM;  // 16384

    unsigned char* sp = (unsigned char*)d_ws;                    // N*256 fp4 packed
    unsigned char* tp = sp + (size_t)N * (D_DIM / 2);            // N*256 fp4 packed
    float* partial = (float*)(tp + (size_t)N * (D_DIM / 2));     // 8192 floats
    const int nPartials = (N / BM) * (N / BN);
    float* corrb = partial + nPartials;                          // N/16 floats
    const int nCorr = N / 16;

    norm_quant_pack_kernel<<<N / 16, 1024, 0, stream>>>(s_in, t_in, sp, tp,
                                                        corrb);
    gemm_loss_kernel<<<nPartials, 256, 0, stream>>>(sp, tp, partial);
    reduce_kernel<<<1, 256, 0, stream>>>(partial, nPartials, corrb, nCorr, N,
                                         (float*)d_out);
}

// Round 8
// 182.577 us; speedup vs baseline: 1.5692x; 1.0768x over previous
//
#include <hip/hip_runtime.h>
#include <stdint.h>

#define TEMPERATURE 0.07f
#define MARGIN 0.1f
#define D_DIM 512          // elements per row
#define BM 128
#define BN 256
#define QSCALE 32.0f       // pre-quantization scale (2^5)
#define SCALE_BYTE 0x7A7A7A7A  // e8m0 2^-5 replicated (compensates QSCALE^2)
#define KS_STRIDE 524288   // bytes per K-step slab: 1024 panels * 512 B

// FP4 (e2m1) packed layout, ks-major (per matrix, N*256 bytes = 4 MB):
//   nibble(row,k) -> byte  (k>>6)*KS_STRIDE + (row>>4)*512
//                        + ((k>>5)&1)*256 + (row&15)*16 + ((k&31)>>1)
//   (k even = low nibble; within-lane k order is irrelevant: both operands
//    use the identical packing, so any k permutation cancels in the dot.)
// mfma_scale_f32_32x32x64_f8f6f4 (cbsz=blgp=4 -> FP4) lane-L fragment of a
// pair-region (32 rows, 1024 B per K-step) at kstep ks: 16 B at
//   ks*KS_STRIDE + pair*1024 + ((L>>4)&1)*512 + (L>>5)*256 + (L&15)*16
// Register-direct feed for BOTH operands (R1 structure, validated at the
// 19.6 TB/s L2 delivery ceiling): no LDS staging, no barriers, no waitcnt.

typedef int v8i32 __attribute__((ext_vector_type(8)));
typedef int v4i32 __attribute__((ext_vector_type(4)));
typedef float f32x16 __attribute__((ext_vector_type(16)));

__device__ __forceinline__ float softplus(float x) {
    return fmaxf(x, 0.0f) + __logf(1.0f + __expf(-fabsf(x)));
}

// e2m1 round-to-nearest encode. Levels: 0,.5,1,1.5,2,3,4,6 (codes 0..7).
__device__ __forceinline__ unsigned enc_fp4(float v) {
    const float ay = fabsf(v);
    int c = 0;
    c += ay > 0.25f;
    c += ay > 0.75f;
    c += ay > 1.25f;
    c += ay > 1.75f;
    c += ay > 2.5f;
    c += ay > 3.5f;
    c += ay > 5.0f;
    return (unsigned)c | ((__float_as_uint(v) >> 28) & 8u);
}

// Fused: L2-normalize row of S and T, quantize to e2m1 fp4 (x32), write the
// ks-major packed layout DIRECTLY (each lane's row-slice = one dword per
// matrix -> no LDS, no barrier), and emit the per-row corr term.
// One wave per row; 4 rows per 256-thread block.
__global__ __launch_bounds__(256) void norm_quant_pack_kernel(
    const float* __restrict__ s_in, const float* __restrict__ t_in,
    unsigned char* __restrict__ sp, unsigned char* __restrict__ tp,
    float* __restrict__ corr) {
    const int row = blockIdx.x * 4 + (threadIdx.x >> 6);
    const int lane = threadIdx.x & 63;
    const float4* s4 = (const float4*)(s_in + (size_t)row * D_DIM);
    const float4* t4 = (const float4*)(t_in + (size_t)row * D_DIM);
    float4 a0 = s4[lane * 2], a1 = s4[lane * 2 + 1];
    float4 b0 = t4[lane * 2], b1 = t4[lane * 2 + 1];
    float ss = a0.x * a0.x + a0.y * a0.y + a0.z * a0.z + a0.w * a0.w +
               a1.x * a1.x + a1.y * a1.y + a1.z * a1.z + a1.w * a1.w;
    float tt = b0.x * b0.x + b0.y * b0.y + b0.z * b0.z + b0.w * b0.w +
               b1.x * b1.x + b1.y * b1.y + b1.z * b1.z + b1.w * b1.w;
    float st = a0.x * b0.x + a0.y * b0.y + a0.z * b0.z + a0.w * b0.w +
               a1.x * b1.x + a1.y * b1.y + a1.z * b1.z + a1.w * b1.w;
#pragma unroll
    for (int off = 32; off > 0; off >>= 1) {
        ss += __shfl_down(ss, off);
        tt += __shfl_down(tt, off);
        st += __shfl_down(st, off);
    }
    ss = __shfl(ss, 0);
    tt = __shfl(tt, 0);
    const float ns = fmaxf(sqrtf(ss), 1e-12f);
    const float nt = fmaxf(sqrtf(tt), 1e-12f);
    if (lane == 0) {
        const float l = st / (ns * nt) * (1.0f / TEMPERATURE);
        corr[row] = softplus(-l - MARGIN) - softplus(l - MARGIN);
    }
    const float is = QSCALE / ns, it = QSCALE / nt;
    // 8 elems (k = 8*lane .. 8*lane+7) -> one u32 of nibbles, k ascending.
    const unsigned ws_ = enc_fp4(a0.x * is) | (enc_fp4(a0.y * is) << 4) |
                         (enc_fp4(a0.z * is) << 8) | (enc_fp4(a0.w * is) << 12) |
                         (enc_fp4(a1.x * is) << 16) | (enc_fp4(a1.y * is) << 20) |
                         (enc_fp4(a1.z * is) << 24) | (enc_fp4(a1.w * is) << 28);
    const unsigned wt_ = enc_fp4(b0.x * it) | (enc_fp4(b0.y * it) << 4) |
                         (enc_fp4(b0.z * it) << 8) | (enc_fp4(b0.w * it) << 12) |
                         (enc_fp4(b1.x * it) << 16) | (enc_fp4(b1.y * it) << 20) |
                         (enc_fp4(b1.z * it) << 24) | (enc_fp4(b1.w * it) << 28);
    // direct ks-major store: slab = lane>>3, khalf = (lane>>2)&1
    const size_t goff = (size_t)(lane >> 3) * KS_STRIDE +
                        (size_t)(row >> 4) * 512 + ((lane >> 2) & 1) * 256 +
                        (row & 15) * 16 + (lane & 3) * 4;
    *(unsigned*)(sp + goff) = ws_;
    *(unsigned*)(tp + goff) = wt_;
}

// 128x256 logits tile per block; 4 waves 2x2, wave tile 64x128 = 2x4 of
// FP4 mfma_scale_f32_32x32x64_f8f6f4 (cbsz=blgp=4). BOTH operands
// register-direct from global (L2-resident; 16-B loads), double-buffered
// one K-step ahead — the R1 structure that measured at the L2 delivery
// ceiling, with fp4 halving every byte. NO LDS staging, NO barriers, NO
// manual waitcnt in the K-loop.
__global__ __launch_bounds__(256, 2) void gemm_loss_kernel(
    const unsigned char* __restrict__ Sp, const unsigned char* __restrict__ Tp,
    float* __restrict__ partial) {
    __shared__ float wsums[4];

    const int tid = threadIdx.x;
    const int wave = tid >> 6;
    const int lane = tid & 63;
    const int wm = wave >> 1;   // 0..1 (M)
    const int wn = wave & 1;    // 0..1 (N)

    // XCD super-tile swizzle (grid 8192 = 128x64 tiles; 16x4-block super-tile
    // per XCD -> S+T fp4 panels L2-resident).
    const int b = blockIdx.x;
    const int xcd = b & 7;
    const int slot = b >> 3;
    const int sidx = slot >> 6;
    const int within = slot & 63;
    const int st_ = sidx * 8 + xcd;
    const int tm = (st_ >> 4) * 16 + (within >> 2);   // 0..127
    const int tn_ = (st_ & 15) * 4 + (within & 3);    // 0..63

    // Per-lane fp4 fragment offset within a pair-region (1024 B)
    const int fl4 =
        ((lane >> 4) & 1) * 512 + (lane >> 5) * 256 + (lane & 15) * 16;

    // A pairs = tm*4 + wm*2 + {0,1};  B pairs = tn_*8 + wn*4 + {0..3}
    const unsigned char* Ab = Sp + (size_t)(tm * 4 + wm * 2) * 1024 + fl4;
    const unsigned char* Bb = Tp + (size_t)(tn_ * 8 + wn * 4) * 1024 + fl4;

    f32x16 acc[2][4];
#pragma unroll
    for (int pa = 0; pa < 2; ++pa)
#pragma unroll
        for (int pb = 0; pb < 4; ++pb)
#pragma unroll
            for (int r = 0; r < 16; ++r) acc[pa][pb][r] = 0.0f;

    v4i32 aF0[2], bF0[4], aF1[2], bF1[4];

    auto load_step = [&](v4i32(&aF)[2], v4i32(&bF)[4], int ks) {
        const size_t ko = (size_t)ks * KS_STRIDE;
#pragma unroll
        for (int pa = 0; pa < 2; ++pa)
            aF[pa] = *(const v4i32*)(Ab + ko + pa * 1024);
#pragma unroll
        for (int pb = 0; pb < 4; ++pb)
            bF[pb] = *(const v4i32*)(Bb + ko + pb * 1024);
    };
    auto mfma_step = [&](v4i32(&aF)[2], v4i32(&bF)[4]) {
        v8i32 aX[2];
#pragma unroll
        for (int pa = 0; pa < 2; ++pa)
            aX[pa] = __builtin_shufflevector(aF[pa], aF[pa], 0, 1, 2, 3, 0, 1,
                                             2, 3);
#pragma unroll
        for (int pb = 0; pb < 4; ++pb) {
            v8i32 bX = __builtin_shufflevector(bF[pb], bF[pb], 0, 1, 2, 3, 0,
                                               1, 2, 3);
#pragma unroll
            for (int pa = 0; pa < 2; ++pa)
                acc[pa][pb] = __builtin_amdgcn_mfma_scale_f32_32x32x64_f8f6f4(
                    aX[pa], bX, acc[pa][pb], 4 /*fp4*/, 4 /*fp4*/,
                    0, SCALE_BYTE, 0, SCALE_BYTE);
        }
    };

    load_step(aF0, bF0, 0);
    load_step(aF1, bF1, 1);
#pragma unroll
    for (int ks = 0; ks < 8; ks += 2) {
        mfma_step(aF0, bF0);
        if (ks + 2 < 8) load_step(aF0, bF0, ks + 2);
        mfma_step(aF1, bF1);
        if (ks + 3 < 8) load_step(aF1, bF1, ks + 3);
    }

    // Uniform epilogue: sum softplus(logit - margin) over all elems.
    // softplus(z) = ln2*( (y+|y|)/2 + log2(1+2^(-|y|)) ), y = z*log2e;
    // log2 terms folded into one v_log per 16-elem group via a product.
    const float C1 = (1.0f / TEMPERATURE) * 1.4426950408889634f;  // log2e/T
    const float C2 = -MARGIN * 1.4426950408889634f;
    float ysum = 0.0f, asum = 0.0f, lsum = 0.0f;
#pragma unroll
    for (int pa = 0; pa < 2; ++pa)
#pragma unroll
        for (int pb = 0; pb < 4; ++pb) {
            float prod = 1.0f;
#pragma unroll
            for (int r = 0; r < 16; ++r) {
                const float y = fmaf(acc[pa][pb][r], C1, C2);
                ysum += y;
                const float ay = fabsf(y);
                asum += ay;
                prod = fmaf(prod, __builtin_amdgcn_exp2f(-ay), prod);
            }
            lsum += __builtin_amdgcn_logf(prod);
        }
    float total =
        fmaf(ysum + asum, 0.5f, lsum) * 0.6931471805599453f;  // * ln2
#pragma unroll
    for (int off = 32; off > 0; off >>= 1) total += __shfl_down(total, off);
    if (lane == 0) wsums[wave] = total;
    __syncthreads();
    if (tid == 0)
        partial[b] = wsums[0] + wsums[1] + wsums[2] + wsums[3];
}

__global__ __launch_bounds__(1024) void reduce_kernel(
    const float* __restrict__ partial, int nPartials,
    const float* __restrict__ corr, int nCorr, int N,
    float* __restrict__ out) {
    const float4* p4 = (const float4*)partial;
    const float4* c4 = (const float4*)corr;
    float sx = 0.0f, sy = 0.0f, sz = 0.0f, sw = 0.0f;
    for (int i = threadIdx.x; i < nPartials / 4; i += 1024) {
        float4 v = p4[i];
        sx += v.x; sy += v.y; sz += v.z; sw += v.w;
    }
    for (int i = threadIdx.x; i < nCorr / 4; i += 1024) {
        float4 v = c4[i];
        sx += v.x; sy += v.y; sz += v.z; sw += v.w;
    }
    float s = (sx + sy) + (sz + sw);
#pragma unroll
    for (int off = 32; off > 0; off >>= 1) s += __shfl_down(s, off);
    __shared__ float ws[16];
    const int wave = threadIdx.x >> 6;
    const int lane = threadIdx.x & 63;
    if (lane == 0) ws[wave] = s;
    __syncthreads();
    if (threadIdx.x == 0) {
        float t = 0.0f;
#pragma unroll
        for (int w = 0; w < 16; ++w) t += ws[w];
        out[0] = t / (float)N;
    }
}

extern "C" void kernel_launch(void* const* d_in, const int* in_sizes, int n_in,
                              void* d_out, int out_size, void* d_ws, size_t ws_size,
                              hipStream_t stream) {
    (void)n_in; (void)out_size; (void)ws_size;
    const float* s_in = (const float*)d_in[0];
    const float* t_in = (const float*)d_in[1];
    const int N = in_sizes[0] / D_DIM;  // 16384

    unsigned char* sp = (unsigned char*)d_ws;                    // N*256 fp4 packed
    unsigned char* tp = sp + (size_t)N * (D_DIM / 2);            // N*256 fp4 packed
    float* partial = (float*)(tp + (size_t)N * (D_DIM / 2));     // 8192 floats
    const int nPartials = (N / BM) * (N / BN);
    float* corr = partial + nPartials;                           // N floats

    norm_quant_pack_kernel<<<N / 4, 256, 0, stream>>>(s_in, t_in, sp, tp,
                                                      corr);
    gemm_loss_kernel<<<nPartials, 256, 0, stream>>>(sp, tp, partial);
    reduce_kernel<<<1, 1024, 0, stream>>>(partial, nPartials, corr, N, N,
                                          (float*)d_out);
}